// Round 9
// baseline (503.363 us; speedup 1.0000x reference)
//
#include <hip/hip_runtime.h>
#include <hip/hip_fp16.h>
#include <math.h>

#define H 16
#define NF 64
#define TPB 256
#define NB 256        // binning blocks (1/CU)
#define NBSHIFT 8     // log2(NB)
#define BTPB 1024     // binning/gat threads per block
#define NSHIFT 6      // bucket = 64 consecutive dst nodes
#define MAXB 2560     // LDS counter capacity (B = ceil(150000/64) = 2344)
#define SBLK 256
#define SITEMS 16     // scan: 4096/block; M=2344*256=600064 -> 147 blocks <= 256
#define SRCMASK 0x3FFFF
#define CAP 3072      // bucket record capacity (avg 2048, Poisson tail << 3072)
#define STAGE_CAP 18752  // >= chunk = ceil(E/NB) = 18750
#define PSPAN 96      // max graphs a 256-node block can span (typ. 2-3)

__device__ __forceinline__ float lrelu(float v){ return v > 0.f ? v : 0.2f*v; }

// ---- derived edge-attention weights: par[0..1] = We1@ae1, par[2..3] = We2@ae2 ----
__global__ void k_prep(const float* __restrict__ We1, const float* __restrict__ ae1,
                       const float* __restrict__ We2, const float* __restrict__ ae2,
                       float* __restrict__ params){
  int t = threadIdx.x;
  if (t < 4){
    const float* We = (t < 2) ? We1 : We2;
    const float* ae = (t < 2) ? ae1 : ae2;
    int r = t & 1;
    float s = 0.f;
    for (int c = 0; c < H; ++c) s += We[r*H + c] * ae[c];
    params[t] = s;
  }
}

// ---- pass 1: per-(bucket, block) histogram in LDS ----
__global__ __launch_bounds__(BTPB) void k_bcount(const int* __restrict__ dst,
    int* __restrict__ cnt, int E, int B, int chunk){
  __shared__ int lcnt[MAXB];
  int blk = blockIdx.x, t = threadIdx.x;
  for (int i = t; i < B; i += BTPB) lcnt[i] = 0;
  __syncthreads();
  int e0 = blk*chunk, e1 = min(E, e0 + chunk);
  for (int e = e0 + t; e < e1; e += BTPB){
    int d = __builtin_nontemporal_load(dst + e);   // NT: don't pollute L2
    atomicAdd(&lcnt[d >> NSHIFT], 1);
  }
  __syncthreads();
  for (int i = t; i < B; i += BTPB) cnt[(size_t)i*NB + blk] = lcnt[i];
}

// ---- scan of the count matrix (bucket-major) -> exclusive ranges ----
__global__ __launch_bounds__(SBLK) void k_scan1(const int* __restrict__ cnt,
    int* __restrict__ part, int M){
  __shared__ int red[SBLK];
  int base = blockIdx.x*SBLK*SITEMS;
  int t = threadIdx.x;
  int s = 0;
  for (int i = 0; i < SITEMS; ++i){
    int idx = base + t*SITEMS + i;
    s += (idx < M) ? cnt[idx] : 0;
  }
  red[t] = s; __syncthreads();
  for (int off = SBLK/2; off > 0; off >>= 1){
    if (t < off) red[t] += red[t+off];
    __syncthreads();
  }
  if (t == 0) part[blockIdx.x] = red[0];
}

__global__ __launch_bounds__(SBLK) void k_scan2(int* __restrict__ part, int nb,
    int* __restrict__ bbase, int B, int E){
  __shared__ int sh[SBLK];
  int t = threadIdx.x;
  int v = (t < nb) ? part[t] : 0;
  sh[t] = v; __syncthreads();
  for (int off = 1; off < SBLK; off <<= 1){
    int add = (t >= off) ? sh[t-off] : 0;
    __syncthreads();
    sh[t] += add;
    __syncthreads();
  }
  if (t < nb) part[t] = sh[t] - v;   // exclusive block offsets
  if (t == 0) bbase[B] = E;
}

// also emits the TRANSPOSED base matrix cntT[blk*B + b] so k_bwrite can read
// its column as two sequential rows (count = next base - base).
__global__ __launch_bounds__(SBLK) void k_scan3(int* __restrict__ cnt,
    const int* __restrict__ part, int* __restrict__ bbase,
    int* __restrict__ cntT, int B, int M){
  __shared__ int sh[SBLK];
  int base = blockIdx.x*SBLK*SITEMS;
  int t = threadIdx.x;
  int loc[SITEMS]; int s = 0;
  for (int i = 0; i < SITEMS; ++i){
    int idx = base + t*SITEMS + i;
    loc[i] = s;
    s += (idx < M) ? cnt[idx] : 0;
  }
  sh[t] = s; __syncthreads();
  for (int off = 1; off < SBLK; off <<= 1){
    int add = (t >= off) ? sh[t-off] : 0;
    __syncthreads();
    sh[t] += add;
    __syncthreads();
  }
  int toff = sh[t] - s + part[blockIdx.x];
  for (int i = 0; i < SITEMS; ++i){
    int idx = base + t*SITEMS + i;
    if (idx < M){
      int excl = toff + loc[i];
      cnt[idx] = excl;                               // in-place per-(bucket,block) base
      cntT[(size_t)(idx & (NB-1))*B + (idx >> NBSHIFT)] = excl;
      if ((idx & (NB-1)) == 0) bbase[idx / NB] = excl;
    }
  }
}

// ---- pass 2: LDS counting-sort of the block's chunk, then BURST write-out.
//      Each (bucket,block) segment of rec is written once, contiguously, by
//      consecutive lanes -> no partial-line thrash. Local per-bucket counts are
//      derived from consecutive exclusive bases in cntT (no histogram pass). ----
__global__ __launch_bounds__(BTPB) void k_bwrite(const int* __restrict__ src,
    const int* __restrict__ dst, const float* __restrict__ attr, const float* __restrict__ wp,
    const int* __restrict__ cntT, int2* __restrict__ rec, int E, int B, int chunk){
  __shared__ int2 stage[STAGE_CAP];
  __shared__ int ex[MAXB];
  __shared__ int wsum[16];
  int blk = blockIdx.x, t = threadIdx.x;
  const int* row0 = cntT + (size_t)blk*B;
  const int* row1 = cntT + (size_t)(blk+1)*B;
  // local exclusive scan of this block's per-bucket counts (ITEMS=3, 3072 >= B)
  {
    int v[3]; int s = 0;
    int base3 = t*3;
    #pragma unroll
    for (int i = 0; i < 3; ++i){
      int idx = base3 + i;
      int c = 0;
      if (idx < B){
        int g0 = row0[idx];
        int g1;
        if (blk < NB-1)      g1 = row1[idx];
        else if (idx < B-1)  g1 = cntT[idx+1];   // row 0 of next bucket
        else                 g1 = E;
        c = g1 - g0;
      }
      v[i] = c; s += c;
    }
    int lane = t & 63, wave = t >> 6;
    int x = s;
    for (int o = 1; o < 64; o <<= 1){
      int y = __shfl_up(x, o);
      if (lane >= o) x += y;
    }
    if (lane == 63) wsum[wave] = x;
    __syncthreads();
    if (t < 16){
      int w = wsum[t];
      int xx = w;
      for (int o = 1; o < 16; o <<= 1){
        int y = __shfl_up(xx, o);
        if (t >= o) xx += y;
      }
      wsum[t] = xx - w;   // exclusive wave base
    }
    __syncthreads();
    int run = wsum[wave] + (x - s);
    #pragma unroll
    for (int i = 0; i < 3; ++i){
      int idx = base3 + i;
      if (idx < B) ex[idx] = run;
      run += v[i];
    }
  }
  __syncthreads();
  // single edge pass: compute record, scatter into LDS at sorted position
  float w0 = wp[0], w1 = wp[1], w2 = wp[2], w3 = wp[3];
  int e0 = blk*chunk, e1 = min(E, e0 + chunk);
  for (int e = e0 + t; e < e1; e += BTPB){
    int d = __builtin_nontemporal_load(dst + e);
    int s = __builtin_nontemporal_load(src + e);
    union { double dd; float2 ff; } u;
    u.dd = __builtin_nontemporal_load((const double*)attr + e);
    float2 a = u.ff;
    int b = d >> NSHIFT;
    __half h1 = __float2half_rn(a.x*w0 + a.y*w1);
    __half h2 = __float2half_rn(a.x*w2 + a.y*w3);
    unsigned uu = (unsigned)__half_as_ushort(h1) | ((unsigned)__half_as_ushort(h2) << 16);
    int pos = atomicAdd(&ex[b], 1);
    stage[pos] = make_int2(s | ((d & 63) << 18), (int)uu);
  }
  __syncthreads();
  // burst write-out: 8 lanes per bucket; segments are contiguous in rec
  int grp = t >> 3, l8 = t & 7;
  for (int b = grp; b < B; b += (BTPB/8)){
    int start = (b == 0) ? 0 : ex[b-1];   // ex advanced by count during scatter
    int end = ex[b];
    if (start == end) continue;
    int gb = row0[b];
    for (int j = start + l8; j < end; j += 8)
      rec[(size_t)gb + (j - start)] = stage[j];
  }
}

// ---- layer-1 fused GAT: per-bucket LDS record-sort + softmax aggregate.
//      ALSO writes back the per-node-SORTED records to rec (y-word rewritten
//      as fp32 d2) plus per-node deg and sum(d2), so layer 2 can skip the
//      histogram/scan/scatter entirely. ----
__global__ __launch_bounds__(BTPB) void k_gatf1(int2* __restrict__ rec,
    const int* __restrict__ bbase, const float* __restrict__ asn, const float* __restrict__ adn,
    const __half* __restrict__ h, const float* __restrict__ bias,
    float* __restrict__ out, int* __restrict__ degg, float* __restrict__ sd2g, int N){
  __shared__ int2 stage[CAP];    // {src|ld<<18, w1 bits}
  __shared__ float d2a[CAP];     // d2 (unsorted)
  __shared__ int2 sorted[CAP];   // {src|ld<<18, w1 bits} sorted by ld
  __shared__ float d2s[CAP];     // d2 sorted
  __shared__ int lcnt[64], lcur[64], sr[2];
  __shared__ float sadn[64], sbias[H], sdacc[64], sdacc2[64];
  int b = blockIdx.x, t = threadIdx.x;
  int node0 = b << NSHIFT;
  if (t < 2) sr[t] = bbase[b + t];
  if (t < 64){
    lcnt[t] = 0;
    sdacc[t] = 0.f;
    sdacc2[t] = 0.f;
    int nn = node0 + t;
    sadn[t] = (nn < N) ? adn[nn] : 0.f;
  }
  if (t >= 64 && t < 64 + H) sbias[t - 64] = bias[t - 64];
  __syncthreads();
  int r0 = sr[0], cnt = sr[1] - r0;
  // phase A: load rec (NT), decode both halves, exp weight, histogram + sums
  for (int i = t; i < cnt; i += BTPB){
    long long raw = __builtin_nontemporal_load((const long long*)(rec + r0 + i));
    int rx = (int)(unsigned)(raw & 0xFFFFFFFFll);
    unsigned u = (unsigned)((unsigned long long)raw >> 32);
    int ld = ((unsigned)rx) >> 18;
    float d1 = __half2float(__ushort_as_half((unsigned short)(u & 0xFFFFu)));
    float d2 = __half2float(__ushort_as_half((unsigned short)(u >> 16)));
    float w = __expf(lrelu(asn[rx & SRCMASK] + sadn[ld] + d1));
    stage[i] = make_int2(rx, __float_as_int(w));
    d2a[i] = d2;
    atomicAdd(&lcnt[ld], 1);
    atomicAdd(&sdacc[ld], d1);
    atomicAdd(&sdacc2[ld], d2);
  }
  __syncthreads();
  // exclusive scan over 64 node counters (wave 0)
  if (t < 64){
    int v = lcnt[t];
    int x = v;
    for (int o = 1; o < 64; o <<= 1){
      int y = __shfl_up(x, o);
      if (t >= o) x += y;
    }
    lcur[t] = x - v;
  }
  __syncthreads();
  // phase C: scatter records + d2 to sorted positions
  for (int i = t; i < cnt; i += BTPB){
    int2 r = stage[i];
    float dd = d2a[i];
    int pos = atomicAdd(&lcur[((unsigned)r.x) >> 18], 1);
    sorted[pos] = r;
    d2s[pos] = dd;
  }
  __syncthreads();
  // write back sorted records for layer 2 ({src|ld, f32 d2}) + per-node meta
  for (int i = t; i < cnt; i += BTPB)
    rec[r0 + i] = make_int2(sorted[i].x, __float_as_int(d2s[i]));
  if (t < 64){
    degg[(b << 6) + t] = lcnt[t];
    sd2g[(b << 6) + t] = sdacc2[t];
  }
  int nl = t >> 4, lane = t & (H-1);
  int n = node0 + nl;
  if (n >= N) return;
  int deg = lcnt[nl];
  int s0 = lcur[nl] - deg;          // lcur advanced by deg during scatter
  float den = 0.f, acc = 0.f;
  for (int j = 0; j < deg; ++j){
    int2 r = sorted[s0 + j];
    float w = __int_as_float(r.y);
    den += w;
    acc += w * __half2float(h[(size_t)(r.x & SRCMASK)*H + lane]);
  }
  // self-loop: edge_attr = mean of incoming attr -> dot = mean of incoming dots
  float lael = sdacc[nl] / fmaxf((float)deg, 1.f);
  float wl = __expf(lrelu(asn[n] + sadn[nl] + lael));
  den += wl;
  acc += wl * __half2float(h[(size_t)n*H + lane]);
  out[(size_t)n*H + lane] = fmaxf(acc/(den + 1e-16f) + sbias[lane], 0.f);
}

// ---- layer-2 fused GAT: records pre-sorted by k_gatf1. No histogram, no
//      scatter, 2 barriers. Phase A is a linear load+weight+store. ----
__global__ __launch_bounds__(BTPB) void k_gatf2(const int2* __restrict__ rec,
    const int* __restrict__ bbase, const int* __restrict__ degg, const float* __restrict__ sd2g,
    const float* __restrict__ asn, const float* __restrict__ adn,
    const __half* __restrict__ h, const float* __restrict__ bias,
    float* __restrict__ out, int N){
  __shared__ int2 sorted[CAP];   // {src|ld<<18, w2 bits} (already ld-sorted)
  __shared__ int lcnt[64], lstart[64], sr[2];
  __shared__ float sadn[64], sbias[H], ssd[64];
  int b = blockIdx.x, t = threadIdx.x;
  int node0 = b << NSHIFT;
  if (t < 2) sr[t] = bbase[b + t];
  if (t < 64){
    int d = degg[(b << 6) + t];
    lcnt[t] = d;
    ssd[t] = sd2g[(b << 6) + t];
    int nn = node0 + t;
    sadn[t] = (nn < N) ? adn[nn] : 0.f;
    int x = d;
    for (int o = 1; o < 64; o <<= 1){
      int y = __shfl_up(x, o);
      if (t >= o) x += y;
    }
    lstart[t] = x - d;
  }
  if (t >= 64 && t < 64 + H) sbias[t - 64] = bias[t - 64];
  __syncthreads();
  int r0 = sr[0], cnt = sr[1] - r0;
  // phase A': linear load + weight; store at position i (already sorted)
  for (int i = t; i < cnt; i += BTPB){
    long long raw = __builtin_nontemporal_load((const long long*)(rec + r0 + i));
    int rx = (int)(unsigned)(raw & 0xFFFFFFFFll);
    float d2 = __int_as_float((int)((unsigned long long)raw >> 32));
    int ld = ((unsigned)rx) >> 18;
    float w = __expf(lrelu(asn[rx & SRCMASK] + sadn[ld] + d2));
    sorted[i] = make_int2(rx, __float_as_int(w));
  }
  __syncthreads();
  int nl = t >> 4, lane = t & (H-1);
  int n = node0 + nl;
  if (n >= N) return;
  int deg = lcnt[nl];
  int s0 = lstart[nl];
  float den = 0.f, acc = 0.f;
  for (int j = 0; j < deg; ++j){
    int2 r = sorted[s0 + j];
    float w = __int_as_float(r.y);
    den += w;
    acc += w * __half2float(h[(size_t)(r.x & SRCMASK)*H + lane]);
  }
  float lael = ssd[nl] / fmaxf((float)deg, 1.f);
  float wl = __expf(lrelu(asn[n] + sadn[nl] + lael));
  den += wl;
  acc += wl * __half2float(h[(size_t)n*H + lane]);
  out[(size_t)n*H + lane] = fmaxf(acc/(den + 1e-16f) + sbias[lane], 0.f);
}

// ---- layer-1 node transform: h = x @ W1 (stored fp16), alpha_src/dst (fp32) ----
__global__ __launch_bounds__(TPB) void k_node1(const float* __restrict__ x, const float* __restrict__ W,
    const float* __restrict__ av_s, const float* __restrict__ av_d,
    __half* __restrict__ hout, float* __restrict__ asn, float* __restrict__ adn, int N){
  __shared__ float sW[NF*H];
  __shared__ float sas[H], sad[H];
  int t = threadIdx.x;
  for (int i = t; i < NF*H; i += TPB) sW[i] = W[i];
  if (t < H){ sas[t] = av_s[t]; sad[t] = av_d[t]; }
  __syncthreads();
  int n = blockIdx.x*TPB + t;
  if (n >= N) return;
  float h[H];
  #pragma unroll
  for (int j = 0; j < H; ++j) h[j] = 0.f;
  const float4* xr = (const float4*)(x + (size_t)n*NF);
  #pragma unroll
  for (int k4 = 0; k4 < NF/4; ++k4){
    float4 xv = xr[k4];
    #pragma unroll
    for (int j = 0; j < H; ++j){
      h[j] += xv.x*sW[(4*k4+0)*H+j] + xv.y*sW[(4*k4+1)*H+j]
            + xv.z*sW[(4*k4+2)*H+j] + xv.w*sW[(4*k4+3)*H+j];
    }
  }
  union { int4 i4[2]; __half hh[H]; } pk;
  #pragma unroll
  for (int j = 0; j < H; ++j) pk.hh[j] = __float2half_rn(h[j]);
  int4* ho = (int4*)(hout + (size_t)n*H);
  ho[0] = pk.i4[0]; ho[1] = pk.i4[1];
  float ss = 0.f, sd = 0.f;
  #pragma unroll
  for (int j = 0; j < H; ++j){ ss += h[j]*sas[j]; sd += h[j]*sad[j]; }
  asn[n] = ss; adn[n] = sd;
}

// ---- BN sum/sumsq: per-block partials, zero global atomics ----
__global__ __launch_bounds__(TPB) void k_stats(const float* __restrict__ B,
    float* __restrict__ partial, int N){
  __shared__ float lds[4][32];
  int t = threadIdx.x;
  int n = blockIdx.x*TPB + t;
  float v[H];
  if (n < N){
    const float4* br = (const float4*)(B + (size_t)n*H);
    float4 a0 = br[0], a1 = br[1], a2 = br[2], a3 = br[3];
    v[0]=a0.x; v[1]=a0.y; v[2]=a0.z; v[3]=a0.w;
    v[4]=a1.x; v[5]=a1.y; v[6]=a1.z; v[7]=a1.w;
    v[8]=a2.x; v[9]=a2.y; v[10]=a2.z; v[11]=a2.w;
    v[12]=a3.x; v[13]=a3.y; v[14]=a3.z; v[15]=a3.w;
  } else {
    #pragma unroll
    for (int f = 0; f < H; ++f) v[f] = 0.f;
  }
  float s[H], q[H];
  #pragma unroll
  for (int f = 0; f < H; ++f){ s[f] = v[f]; q[f] = v[f]*v[f]; }
  for (int m = 1; m < 64; m <<= 1){
    #pragma unroll
    for (int f = 0; f < H; ++f){
      s[f] += __shfl_xor(s[f], m);
      q[f] += __shfl_xor(q[f], m);
    }
  }
  int wave = t >> 6, lane = t & 63;
  if (lane == 0){
    #pragma unroll
    for (int f = 0; f < H; ++f){ lds[wave][f] = s[f]; lds[wave][H+f] = q[f]; }
  }
  __syncthreads();
  if (t < 32)
    partial[(size_t)blockIdx.x*32 + t] = lds[0][t] + lds[1][t] + lds[2][t] + lds[3][t];
}

// ---- final BN reduction over block partials + scale/shift ----
__global__ __launch_bounds__(256) void k_bnprep(const float* __restrict__ partial, int nb,
    const float* __restrict__ gamma, const float* __restrict__ beta,
    float* __restrict__ scale, float* __restrict__ shift, int N){
  __shared__ float red[256];
  __shared__ float tot[32];
  int t = threadIdx.x;
  int f = t & 31, c = t >> 5;        // 8 chunks x 32 features
  float s = 0.f;
  for (int b = c; b < nb; b += 8) s += partial[(size_t)b*32 + f];
  red[c*32 + f] = s;
  __syncthreads();
  if (t < 32){
    float S = 0.f;
    #pragma unroll
    for (int cc = 0; cc < 8; ++cc) S += red[cc*32 + t];
    tot[t] = S;
  }
  __syncthreads();
  if (t < H){
    float inv = 1.f / (float)N;
    float mu  = tot[t] * inv;
    float var = tot[H+t] * inv - mu*mu;
    float sc  = gamma[t] * rsqrtf(var + 1e-5f);
    scale[t] = sc;
    shift[t] = beta[t] - mu*sc;
  }
}

// ---- layer-2 node transform: BN + h = xn @ W2 (stored fp16) + alphas ----
__global__ __launch_bounds__(TPB) void k_node2(const float* __restrict__ Bin, const float* __restrict__ scale,
    const float* __restrict__ shift, const float* __restrict__ W,
    const float* __restrict__ av_s, const float* __restrict__ av_d,
    __half* __restrict__ hout, float* __restrict__ asn, float* __restrict__ adn, int N){
  __shared__ float sW[H*H];
  __shared__ float ssc[H], ssh[H], sas[H], sad[H];
  int t = threadIdx.x;
  if (t < H*H) sW[t] = W[t];
  if (t < H){ ssc[t] = scale[t]; ssh[t] = shift[t]; sas[t] = av_s[t]; sad[t] = av_d[t]; }
  __syncthreads();
  int n = blockIdx.x*TPB + t;
  if (n >= N) return;
  const float4* br = (const float4*)(Bin + (size_t)n*H);
  float4 a0 = br[0], a1 = br[1], a2 = br[2], a3 = br[3];
  float xn[H] = {a0.x,a0.y,a0.z,a0.w, a1.x,a1.y,a1.z,a1.w,
                 a2.x,a2.y,a2.z,a2.w, a3.x,a3.y,a3.z,a3.w};
  #pragma unroll
  for (int f = 0; f < H; ++f) xn[f] = xn[f]*ssc[f] + ssh[f];
  float h[H];
  #pragma unroll
  for (int j = 0; j < H; ++j) h[j] = 0.f;
  #pragma unroll
  for (int k = 0; k < H; ++k){
    float xv = xn[k];
    #pragma unroll
    for (int j = 0; j < H; ++j) h[j] += xv * sW[k*H+j];
  }
  union { int4 i4[2]; __half hh[H]; } pk;
  #pragma unroll
  for (int j = 0; j < H; ++j) pk.hh[j] = __float2half_rn(h[j]);
  int4* ho = (int4*)(hout + (size_t)n*H);
  ho[0] = pk.i4[0]; ho[1] = pk.i4[1];
  float ss = 0.f, sd = 0.f;
  #pragma unroll
  for (int j = 0; j < H; ++j){ ss += h[j]*sas[j]; sd += h[j]*sad[j]; }
  asn[n] = ss; adn[n] = sd;
}

// ---- mean-pool: LDS per-block segmented partials (batch sorted -> block spans
//      a contiguous graph range, typ. 2-3). One global atomicAdd per
//      (touched graph, feature) per block instead of per-lane atomics. ----
__global__ __launch_bounds__(TPB) void k_pool(const float* __restrict__ B,
    const int* __restrict__ batch, float* __restrict__ pooled, float* __restrict__ gcnt, int N){
  __shared__ float acc[PSPAN*H];
  __shared__ float cacc[PSPAN];
  __shared__ int sg[2];
  int t = threadIdx.x;
  int n0 = blockIdx.x*TPB;
  int n = n0 + t;
  if (t == 0){
    sg[0] = batch[n0];
    int n1 = min(n0 + TPB - 1, N - 1);
    sg[1] = batch[n1];
  }
  __syncthreads();
  int gmin = sg[0];
  int span = sg[1] - gmin + 1;
  bool fits = (span <= PSPAN);        // block-uniform
  if (fits){
    for (int i = t; i < span*H; i += TPB) acc[i] = 0.f;
    for (int i = t; i < span; i += TPB) cacc[i] = 0.f;
    __syncthreads();
  }
  int lane = t & 63;
  bool valid = n < N;
  int g = valid ? batch[n] : -1;
  float v[H];
  if (valid){
    const float4* br = (const float4*)(B + (size_t)n*H);
    float4 a0 = br[0], a1 = br[1], a2 = br[2], a3 = br[3];
    v[0]=a0.x; v[1]=a0.y; v[2]=a0.z; v[3]=a0.w;
    v[4]=a1.x; v[5]=a1.y; v[6]=a1.z; v[7]=a1.w;
    v[8]=a2.x; v[9]=a2.y; v[10]=a2.z; v[11]=a2.w;
    v[12]=a3.x; v[13]=a3.y; v[14]=a3.z; v[15]=a3.w;
  } else {
    #pragma unroll
    for (int f = 0; f < H; ++f) v[f] = 0.f;
  }
  int g0 = __shfl(g, 0);
  bool allsame = __all(valid && g == g0);
  if (fits){
    if (allsame){
      float s[H];
      #pragma unroll
      for (int f = 0; f < H; ++f) s[f] = v[f];
      for (int m = 1; m < 64; m <<= 1){
        #pragma unroll
        for (int f = 0; f < H; ++f) s[f] += __shfl_xor(s[f], m);
      }
      if (lane == 0){
        float* p = acc + (g0 - gmin)*H;
        #pragma unroll
        for (int f = 0; f < H; ++f) atomicAdd(&p[f], s[f]);
        atomicAdd(&cacc[g0 - gmin], 64.f);
      }
    } else if (valid){
      float* p = acc + (g - gmin)*H;
      #pragma unroll
      for (int f = 0; f < H; ++f) atomicAdd(&p[f], v[f]);
      atomicAdd(&cacc[g - gmin], 1.f);
    }
    __syncthreads();
    // flush block partials: ~span*17 global atomics, low per-address multiplicity
    for (int i = t; i < span*H; i += TPB){
      float a = acc[i];
      if (a != 0.f) atomicAdd(&pooled[(size_t)gmin*H + i], a);
    }
    for (int i = t; i < span; i += TPB){
      float c = cacc[i];
      if (c != 0.f) atomicAdd(&gcnt[gmin + i], c);
    }
  } else {
    // safety fallback (never expected): direct global atomics
    if (allsame){
      float s[H];
      #pragma unroll
      for (int f = 0; f < H; ++f) s[f] = v[f];
      for (int m = 1; m < 64; m <<= 1){
        #pragma unroll
        for (int f = 0; f < H; ++f) s[f] += __shfl_xor(s[f], m);
      }
      if (lane == 0){
        float* p = pooled + (size_t)g0*H;
        #pragma unroll
        for (int f = 0; f < H; ++f) atomicAdd(&p[f], s[f]);
        atomicAdd(&gcnt[g0], 64.f);
      }
    } else if (valid){
      float* p = pooled + (size_t)g*H;
      #pragma unroll
      for (int f = 0; f < H; ++f) atomicAdd(&p[f], v[f]);
      atomicAdd(&gcnt[g], 1.f);
    }
  }
}

// ---- D2RL head: one block of 512 threads (one per graph) ----
__device__ void block_stats16(const float* v, float* mu, float* rs,
                              float* wsum, float* wsq, int G){
  float s[H], q[H];
  #pragma unroll
  for (int f = 0; f < H; ++f){ s[f] = v[f]; q[f] = v[f]*v[f]; }
  for (int m = 1; m < 64; m <<= 1){
    #pragma unroll
    for (int f = 0; f < H; ++f){
      s[f] += __shfl_xor(s[f], m);
      q[f] += __shfl_xor(q[f], m);
    }
  }
  int wave = threadIdx.x >> 6, lane = threadIdx.x & 63;
  if (lane == 0){
    #pragma unroll
    for (int f = 0; f < H; ++f){ wsum[wave*H+f] = s[f]; wsq[wave*H+f] = q[f]; }
  }
  __syncthreads();
  int t = threadIdx.x;
  if (t < H){
    float S = 0.f, Q = 0.f;
    for (int w = 0; w < 8; ++w){ S += wsum[w*H+t]; Q += wsq[w*H+t]; }
    float m_ = S / (float)G;
    float var = Q / (float)G - m_*m_;
    mu[t] = m_;
    rs[t] = rsqrtf(var + 1e-5f);
  }
  __syncthreads();
}

__global__ __launch_bounds__(512) void k_head(const float* __restrict__ pooled, const float* __restrict__ gcnt,
    const float* __restrict__ g1, const float* __restrict__ be1,
    const float* __restrict__ Wl1, const float* __restrict__ bl1,
    const float* __restrict__ g2, const float* __restrict__ be2,
    const float* __restrict__ Wl2, const float* __restrict__ bl2,
    const float* __restrict__ g3, const float* __restrict__ be3,
    const float* __restrict__ Wl3, const float* __restrict__ bl3,
    const float* __restrict__ Wo, const float* __restrict__ bo,
    float* __restrict__ out, int G){
  __shared__ float wsum[8*H], wsq[8*H];
  __shared__ float pmu[H], prs[H], smu[H], srs[H];
  int g = threadIdx.x;
  float p[H];
  if (g < G){
    float c = fmaxf(gcnt[g], 1.f);
    #pragma unroll
    for (int f = 0; f < H; ++f) p[f] = pooled[(size_t)g*H+f] / c;
  } else {
    #pragma unroll
    for (int f = 0; f < H; ++f) p[f] = 0.f;
  }
  block_stats16(p, pmu, prs, wsum, wsq, G);
  float xn[H], z[H];
  #pragma unroll
  for (int f = 0; f < H; ++f) xn[f] = g1[f]*(p[f]-pmu[f])*prs[f] + be1[f];
  #pragma unroll
  for (int j = 0; j < H; ++j) z[j] = bl1[j];
  for (int k = 0; k < H; ++k){
    float xv = xn[k];
    #pragma unroll
    for (int j = 0; j < H; ++j) z[j] += xv * Wl1[k*H+j];
  }
  #pragma unroll
  for (int j = 0; j < H; ++j) z[j] = fmaxf(z[j], 0.f);
  block_stats16(z, smu, srs, wsum, wsq, G);
  float x2[2*H], z2[H];
  #pragma unroll
  for (int f = 0; f < H; ++f){
    x2[f]   = g2[f]  *(z[f]-smu[f])*srs[f] + be2[f];
    x2[H+f] = g2[H+f]*(p[f]-pmu[f])*prs[f] + be2[H+f];
  }
  #pragma unroll
  for (int j = 0; j < H; ++j) z2[j] = bl2[j];
  for (int k = 0; k < 2*H; ++k){
    float xv = x2[k];
    #pragma unroll
    for (int j = 0; j < H; ++j) z2[j] += xv * Wl2[k*H+j];
  }
  #pragma unroll
  for (int j = 0; j < H; ++j) z2[j] = fmaxf(z2[j], 0.f);
  block_stats16(z2, smu, srs, wsum, wsq, G);
  float x3[2*H], z3[H];
  #pragma unroll
  for (int f = 0; f < H; ++f){
    x3[f]   = g3[f]  *(z2[f]-smu[f])*srs[f] + be3[f];
    x3[H+f] = g3[H+f]*(p[f]-pmu[f])*prs[f] + be3[H+f];
  }
  #pragma unroll
  for (int j = 0; j < H; ++j) z3[j] = bl3[j];
  for (int k = 0; k < 2*H; ++k){
    float xv = x3[k];
    #pragma unroll
    for (int j = 0; j < H; ++j) z3[j] += xv * Wl3[k*H+j];
  }
  #pragma unroll
  for (int j = 0; j < H; ++j) z3[j] = fmaxf(z3[j], 0.f);
  if (g < G){
    float o = bo[0];
    #pragma unroll
    for (int j = 0; j < H; ++j) o += z3[j]*Wo[j];
    out[g] = o;
  }
}

extern "C" void kernel_launch(void* const* d_in, const int* in_sizes, int n_in,
                              void* d_out, int out_size, void* d_ws, size_t ws_size,
                              hipStream_t stream) {
  const float* x     = (const float*)d_in[0];
  const int*   ei    = (const int*)d_in[1];
  const float* attr  = (const float*)d_in[2];
  const int*   batch = (const int*)d_in[3];
  const float* W1  = (const float*)d_in[4];
  const float* We1 = (const float*)d_in[5];
  const float* as1 = (const float*)d_in[6];
  const float* ad1 = (const float*)d_in[7];
  const float* ae1 = (const float*)d_in[8];
  const float* b1  = (const float*)d_in[9];
  const float* bn1g = (const float*)d_in[10];
  const float* bn1b = (const float*)d_in[11];
  const float* W2  = (const float*)d_in[12];
  const float* We2 = (const float*)d_in[13];
  const float* as2 = (const float*)d_in[14];
  const float* ad2 = (const float*)d_in[15];
  const float* ae2 = (const float*)d_in[16];
  const float* b2  = (const float*)d_in[17];
  const float* bnl1g = (const float*)d_in[18];
  const float* bnl1b = (const float*)d_in[19];
  const float* Wl1 = (const float*)d_in[20];
  const float* bl1 = (const float*)d_in[21];
  const float* bnl2g = (const float*)d_in[22];
  const float* bnl2b = (const float*)d_in[23];
  const float* Wl2 = (const float*)d_in[24];
  const float* bl2 = (const float*)d_in[25];
  const float* bnl3g = (const float*)d_in[26];
  const float* bnl3b = (const float*)d_in[27];
  const float* Wl3 = (const float*)d_in[28];
  const float* bl3 = (const float*)d_in[29];
  const float* Wo  = (const float*)d_in[30];
  const float* bo  = (const float*)d_in[31];

  int N = in_sizes[0] / NF;
  int E = in_sizes[1] / 2;
  int G = out_size;
  const int* srcp = ei;
  const int* dstp = ei + E;

  int B     = (N + 63) >> 6;                         // 64-node buckets (2344)
  int M     = B * NB;                                // count-matrix size (600064)
  int chunk = (E + NB - 1) / NB;                     // edges per binning block (18750)
  int nbN   = (N + TPB - 1)/TPB;
  int nbS   = (M + SBLK*SITEMS - 1)/(SBLK*SITEMS);   // scan blocks (147 <= 256)

  // ---- workspace layout (rec persists through both GAT layers; no aliasing) ----
  char* wsb = (char*)d_ws;
  int2*  rec = (int2*)wsb;                           // 8B * E
  char* p = wsb + (size_t)8*E;
  __half* A = (__half*)p;     p += (size_t)2*H*N;    // h table (fp16, 4.8 MB)
  float* Bv  = (float*)p;     p += (size_t)16*N*4;   // layer output (fp32)
  float* asn = (float*)p;     p += (size_t)N*4;
  float* adn = (float*)p;     p += (size_t)N*4;
  int*   cnt     = (int*)p;   p += (size_t)4*M;      // per-(bucket,block) counts -> bases
  int*   cntT    = (int*)p;   p += (size_t)4*M;      // transposed bases [blk][b]
  int*   bbase   = (int*)p;   p += (size_t)4*(B+1);
  int*   part    = (int*)p;   p += (size_t)4*256;
  float* par     = (float*)p; p += 4*64;             // [0..3]=wp [4..19]=scale [20..35]=shift
  float* pooled  = (float*)p; p += (size_t)4*G*H;
  float* gcnt    = (float*)p; p += (size_t)4*G;
  float* partial = (float*)p; p += (size_t)4*nbN*32;
  int*   degg    = (int*)p;   p += (size_t)4*B*64;   // per-node degree (sorted reuse)
  float* sd2g    = (float*)p; p += (size_t)4*B*64;   // per-node sum(d2)

  float* bnscale = par + 4;
  float* bnshift = par + 20;

  // zero-init (ws is re-poisoned 0xAA before every launch)
  hipMemsetAsync(pooled, 0, (size_t)(G*H + G)*sizeof(float), stream);

  k_prep<<<1, 64, 0, stream>>>(We1, ae1, We2, ae2, par);

  // ---- binning: two-pass exclusive-range, 8B records, no global atomics ----
  k_bcount<<<NB, BTPB, 0, stream>>>(dstp, cnt, E, B, chunk);
  k_scan1<<<nbS, SBLK, 0, stream>>>(cnt, part, M);
  k_scan2<<<1, SBLK, 0, stream>>>(part, nbS, bbase, B, E);
  k_scan3<<<nbS, SBLK, 0, stream>>>(cnt, part, bbase, cntT, B, M);
  k_bwrite<<<NB, BTPB, 0, stream>>>(srcp, dstp, attr, par, cntT, rec, E, B, chunk);

  // ---- layer 1 (also emits sorted rec + per-node meta for layer 2) ----
  k_node1<<<nbN, TPB, 0, stream>>>(x, W1, as1, ad1, A, asn, adn, N);
  k_gatf1<<<B, BTPB, 0, stream>>>(rec, bbase, asn, adn, A, b1, Bv, degg, sd2g, N);
  k_stats<<<nbN, TPB, 0, stream>>>(Bv, partial, N);
  k_bnprep<<<1, 256, 0, stream>>>(partial, nbN, bn1g, bn1b, bnscale, bnshift, N);

  // ---- layer 2 (pre-sorted fast path) ----
  k_node2<<<nbN, TPB, 0, stream>>>(Bv, bnscale, bnshift, W2, as2, ad2, A, asn, adn, N);
  k_gatf2<<<B, BTPB, 0, stream>>>(rec, bbase, degg, sd2g, asn, adn, A, b2, Bv, N);

  // ---- pool + head ----
  k_pool<<<nbN, TPB, 0, stream>>>(Bv, batch, pooled, gcnt, N);
  k_head<<<1, 512, 0, stream>>>(pooled, gcnt, bnl1g, bnl1b, Wl1, bl1, bnl2g, bnl2b, Wl2, bl2,
                                bnl3g, bnl3b, Wl3, bl3, Wo, bo, (float*)d_out, G);
}

// Round 10
// 485.179 us; speedup vs baseline: 1.0375x; 1.0375x over previous
//
#include <hip/hip_runtime.h>
#include <hip/hip_fp16.h>
#include <math.h>

#define H 16
#define NF 64
#define TPB 256
#define NB 256        // binning blocks (1/CU)
#define NBSHIFT 8     // log2(NB)
#define BTPB 1024     // binning threads per block
#define GTPB 512      // gat threads per block (64 nodes x 8 lanes)
#define NSHIFT 6      // bucket = 64 consecutive dst nodes
#define MAXB 2560     // LDS counter capacity (B = ceil(150000/64) = 2344)
#define SBLK 256
#define SITEMS 16     // scan: 4096/block; M=2344*256=600064 -> 147 blocks <= 256
#define SRCMASK 0x3FFFF
#define CAP 3072      // bucket record capacity (avg 2048, Poisson tail << 3072)
#define STAGE_CAP 18752  // >= chunk = ceil(E/NB) = 18750
#define PSPAN 96      // max graphs a 256-node block can span (typ. 2-3)

__device__ __forceinline__ float lrelu(float v){ return v > 0.f ? v : 0.2f*v; }

// ---- derived edge-attention weights: par[0..1] = We1@ae1, par[2..3] = We2@ae2 ----
__global__ void k_prep(const float* __restrict__ We1, const float* __restrict__ ae1,
                       const float* __restrict__ We2, const float* __restrict__ ae2,
                       float* __restrict__ params){
  int t = threadIdx.x;
  if (t < 4){
    const float* We = (t < 2) ? We1 : We2;
    const float* ae = (t < 2) ? ae1 : ae2;
    int r = t & 1;
    float s = 0.f;
    for (int c = 0; c < H; ++c) s += We[r*H + c] * ae[c];
    params[t] = s;
  }
}

// ---- pass 1: per-(bucket, block) histogram in LDS ----
__global__ __launch_bounds__(BTPB) void k_bcount(const int* __restrict__ dst,
    int* __restrict__ cnt, int E, int B, int chunk){
  __shared__ int lcnt[MAXB];
  int blk = blockIdx.x, t = threadIdx.x;
  for (int i = t; i < B; i += BTPB) lcnt[i] = 0;
  __syncthreads();
  int e0 = blk*chunk, e1 = min(E, e0 + chunk);
  for (int e = e0 + t; e < e1; e += BTPB){
    int d = __builtin_nontemporal_load(dst + e);   // NT: don't pollute L2
    atomicAdd(&lcnt[d >> NSHIFT], 1);
  }
  __syncthreads();
  for (int i = t; i < B; i += BTPB) cnt[(size_t)i*NB + blk] = lcnt[i];
}

// ---- scan of the count matrix (bucket-major) -> exclusive ranges ----
__global__ __launch_bounds__(SBLK) void k_scan1(const int* __restrict__ cnt,
    int* __restrict__ part, int M){
  __shared__ int red[SBLK];
  int base = blockIdx.x*SBLK*SITEMS;
  int t = threadIdx.x;
  int s = 0;
  for (int i = 0; i < SITEMS; ++i){
    int idx = base + t*SITEMS + i;
    s += (idx < M) ? cnt[idx] : 0;
  }
  red[t] = s; __syncthreads();
  for (int off = SBLK/2; off > 0; off >>= 1){
    if (t < off) red[t] += red[t+off];
    __syncthreads();
  }
  if (t == 0) part[blockIdx.x] = red[0];
}

__global__ __launch_bounds__(SBLK) void k_scan2(int* __restrict__ part, int nb,
    int* __restrict__ bbase, int B, int E){
  __shared__ int sh[SBLK];
  int t = threadIdx.x;
  int v = (t < nb) ? part[t] : 0;
  sh[t] = v; __syncthreads();
  for (int off = 1; off < SBLK; off <<= 1){
    int add = (t >= off) ? sh[t-off] : 0;
    __syncthreads();
    sh[t] += add;
    __syncthreads();
  }
  if (t < nb) part[t] = sh[t] - v;   // exclusive block offsets
  if (t == 0) bbase[B] = E;
}

// also emits the TRANSPOSED base matrix cntT[blk*B + b] so k_bwrite can read
// its column as two sequential rows (count = next base - base).
__global__ __launch_bounds__(SBLK) void k_scan3(int* __restrict__ cnt,
    const int* __restrict__ part, int* __restrict__ bbase,
    int* __restrict__ cntT, int B, int M){
  __shared__ int sh[SBLK];
  int base = blockIdx.x*SBLK*SITEMS;
  int t = threadIdx.x;
  int loc[SITEMS]; int s = 0;
  for (int i = 0; i < SITEMS; ++i){
    int idx = base + t*SITEMS + i;
    loc[i] = s;
    s += (idx < M) ? cnt[idx] : 0;
  }
  sh[t] = s; __syncthreads();
  for (int off = 1; off < SBLK; off <<= 1){
    int add = (t >= off) ? sh[t-off] : 0;
    __syncthreads();
    sh[t] += add;
    __syncthreads();
  }
  int toff = sh[t] - s + part[blockIdx.x];
  for (int i = 0; i < SITEMS; ++i){
    int idx = base + t*SITEMS + i;
    if (idx < M){
      int excl = toff + loc[i];
      cnt[idx] = excl;                               // in-place per-(bucket,block) base
      cntT[(size_t)(idx & (NB-1))*B + (idx >> NBSHIFT)] = excl;
      if ((idx & (NB-1)) == 0) bbase[idx / NB] = excl;
    }
  }
}

// ---- pass 2: LDS counting-sort of the block's chunk, then BURST write-out.
//      Each (bucket,block) segment of rec is written once, contiguously, by
//      consecutive lanes -> no partial-line thrash. Local per-bucket counts are
//      derived from consecutive exclusive bases in cntT (no histogram pass). ----
__global__ __launch_bounds__(BTPB) void k_bwrite(const int* __restrict__ src,
    const int* __restrict__ dst, const float* __restrict__ attr, const float* __restrict__ wp,
    const int* __restrict__ cntT, int2* __restrict__ rec, int E, int B, int chunk){
  __shared__ int2 stage[STAGE_CAP];
  __shared__ int ex[MAXB];
  __shared__ int wsum[16];
  int blk = blockIdx.x, t = threadIdx.x;
  const int* row0 = cntT + (size_t)blk*B;
  const int* row1 = cntT + (size_t)(blk+1)*B;
  // local exclusive scan of this block's per-bucket counts (ITEMS=3, 3072 >= B)
  {
    int v[3]; int s = 0;
    int base3 = t*3;
    #pragma unroll
    for (int i = 0; i < 3; ++i){
      int idx = base3 + i;
      int c = 0;
      if (idx < B){
        int g0 = row0[idx];
        int g1;
        if (blk < NB-1)      g1 = row1[idx];
        else if (idx < B-1)  g1 = cntT[idx+1];   // row 0 of next bucket
        else                 g1 = E;
        c = g1 - g0;
      }
      v[i] = c; s += c;
    }
    int lane = t & 63, wave = t >> 6;
    int x = s;
    for (int o = 1; o < 64; o <<= 1){
      int y = __shfl_up(x, o);
      if (lane >= o) x += y;
    }
    if (lane == 63) wsum[wave] = x;
    __syncthreads();
    if (t < 16){
      int w = wsum[t];
      int xx = w;
      for (int o = 1; o < 16; o <<= 1){
        int y = __shfl_up(xx, o);
        if (t >= o) xx += y;
      }
      wsum[t] = xx - w;   // exclusive wave base
    }
    __syncthreads();
    int run = wsum[wave] + (x - s);
    #pragma unroll
    for (int i = 0; i < 3; ++i){
      int idx = base3 + i;
      if (idx < B) ex[idx] = run;
      run += v[i];
    }
  }
  __syncthreads();
  // single edge pass: compute record, scatter into LDS at sorted position
  float w0 = wp[0], w1 = wp[1], w2 = wp[2], w3 = wp[3];
  int e0 = blk*chunk, e1 = min(E, e0 + chunk);
  for (int e = e0 + t; e < e1; e += BTPB){
    int d = __builtin_nontemporal_load(dst + e);
    int s = __builtin_nontemporal_load(src + e);
    union { double dd; float2 ff; } u;
    u.dd = __builtin_nontemporal_load((const double*)attr + e);
    float2 a = u.ff;
    int b = d >> NSHIFT;
    __half h1 = __float2half_rn(a.x*w0 + a.y*w1);
    __half h2 = __float2half_rn(a.x*w2 + a.y*w3);
    unsigned uu = (unsigned)__half_as_ushort(h1) | ((unsigned)__half_as_ushort(h2) << 16);
    int pos = atomicAdd(&ex[b], 1);
    stage[pos] = make_int2(s | ((d & 63) << 18), (int)uu);
  }
  __syncthreads();
  // burst write-out: 8 lanes per bucket; segments are contiguous in rec
  int grp = t >> 3, l8 = t & 7;
  for (int b = grp; b < B; b += (BTPB/8)){
    int start = (b == 0) ? 0 : ex[b-1];   // ex advanced by count during scatter
    int end = ex[b];
    if (start == end) continue;
    int gb = row0[b];
    for (int j = start + l8; j < end; j += 8)
      rec[(size_t)gb + (j - start)] = stage[j];
  }
}

// ---- fused GAT: per-bucket LDS RECORD-sort + softmax aggregate ----
// 512 threads = 64 nodes x 8 lanes (lane = feature PAIR, half2 loads).
// One phase-D wave-load now services 8 edges (8 distinct 32B rows, 256B per
// instruction) vs 4 before -> half the gather wave-instructions per edge.
template<int SEL>
__global__ __launch_bounds__(GTPB) void k_gatf(const int2* __restrict__ rec,
    const int* __restrict__ bbase, const float* __restrict__ asn, const float* __restrict__ adn,
    const __half* __restrict__ h, const float* __restrict__ bias,
    float* __restrict__ out, int N){
  __shared__ int2 stage[CAP];    // raw: {src|ld<<18, w bits}
  __shared__ int2 sorted[CAP];   // sorted by ld
  __shared__ int lcnt[64], lcur[64], sr[2];
  __shared__ float sadn[64], sbias[H], sdacc[64];
  int b = blockIdx.x, t = threadIdx.x;
  int node0 = b << NSHIFT;
  if (t < 2) sr[t] = bbase[b + t];
  if (t < 64){
    lcnt[t] = 0;
    sdacc[t] = 0.f;
    int nn = node0 + t;
    sadn[t] = (nn < N) ? adn[nn] : 0.f;
  }
  if (t >= 64 && t < 64 + H) sbias[t - 64] = bias[t - 64];
  __syncthreads();
  int r0 = sr[0], cnt = sr[1] - r0;
  // phase A: load rec (NT), decode, asn gather, exp weight, histogram + sd
  for (int i = t; i < cnt; i += GTPB){
    long long raw = __builtin_nontemporal_load((const long long*)(rec + r0 + i));
    int rx = (int)(unsigned)(raw & 0xFFFFFFFFll);
    unsigned u = (unsigned)((unsigned long long)raw >> 32);
    int ld = ((unsigned)rx) >> 18;
    float d = __half2float(__ushort_as_half((unsigned short)(SEL ? (u >> 16) : (u & 0xFFFFu))));
    float w = __expf(lrelu(asn[rx & SRCMASK] + sadn[ld] + d));
    stage[i] = make_int2(rx, __float_as_int(w));
    atomicAdd(&lcnt[ld], 1);
    atomicAdd(&sdacc[ld], d);
  }
  __syncthreads();
  // exclusive scan over 64 node counters (wave 0)
  if (t < 64){
    int v = lcnt[t];
    int x = v;
    for (int o = 1; o < 64; o <<= 1){
      int y = __shfl_up(x, o);
      if (t >= o) x += y;
    }
    lcur[t] = x - v;
  }
  __syncthreads();
  // phase C: pure LDS scatter of full records to sorted positions
  for (int i = t; i < cnt; i += GTPB){
    int2 r = stage[i];
    sorted[atomicAdd(&lcur[((unsigned)r.x) >> 18], 1)] = r;
  }
  __syncthreads();
  int nl = t >> 3, l2 = t & 7;     // node, feature-pair lane
  int n = node0 + nl;
  if (n >= N) return;
  const __half2* h2 = (const __half2*)h;
  float b0 = sbias[2*l2], b1 = sbias[2*l2 + 1];
  int deg = lcnt[nl];
  int s0 = lcur[nl] - deg;          // lcur advanced by deg during scatter
  float den = 0.f, acc0 = 0.f, acc1 = 0.f;
  for (int j = 0; j < deg; ++j){
    int2 r = sorted[s0 + j];
    float w = __int_as_float(r.y);
    float2 f = __half22float2(h2[(size_t)(r.x & SRCMASK)*8 + l2]);
    den += w;
    acc0 += w * f.x;
    acc1 += w * f.y;
  }
  // self-loop: edge_attr = mean of incoming attr -> dot = mean of incoming dots
  float lael = sdacc[nl] / fmaxf((float)deg, 1.f);
  float wl = __expf(lrelu(asn[n] + sadn[nl] + lael));
  float2 fs = __half22float2(h2[(size_t)n*8 + l2]);
  den += wl;
  acc0 += wl * fs.x;
  acc1 += wl * fs.y;
  float inv = 1.f / (den + 1e-16f);
  ((float2*)out)[(size_t)n*8 + l2] =
      make_float2(fmaxf(acc0*inv + b0, 0.f), fmaxf(acc1*inv + b1, 0.f));
}

// ---- layer-1 node transform: h = x @ W1 (stored fp16), alpha_src/dst (fp32) ----
__global__ __launch_bounds__(TPB) void k_node1(const float* __restrict__ x, const float* __restrict__ W,
    const float* __restrict__ av_s, const float* __restrict__ av_d,
    __half* __restrict__ hout, float* __restrict__ asn, float* __restrict__ adn, int N){
  __shared__ float sW[NF*H];
  __shared__ float sas[H], sad[H];
  int t = threadIdx.x;
  for (int i = t; i < NF*H; i += TPB) sW[i] = W[i];
  if (t < H){ sas[t] = av_s[t]; sad[t] = av_d[t]; }
  __syncthreads();
  int n = blockIdx.x*TPB + t;
  if (n >= N) return;
  float h[H];
  #pragma unroll
  for (int j = 0; j < H; ++j) h[j] = 0.f;
  const float4* xr = (const float4*)(x + (size_t)n*NF);
  #pragma unroll
  for (int k4 = 0; k4 < NF/4; ++k4){
    float4 xv = xr[k4];
    #pragma unroll
    for (int j = 0; j < H; ++j){
      h[j] += xv.x*sW[(4*k4+0)*H+j] + xv.y*sW[(4*k4+1)*H+j]
            + xv.z*sW[(4*k4+2)*H+j] + xv.w*sW[(4*k4+3)*H+j];
    }
  }
  union { int4 i4[2]; __half hh[H]; } pk;
  #pragma unroll
  for (int j = 0; j < H; ++j) pk.hh[j] = __float2half_rn(h[j]);
  int4* ho = (int4*)(hout + (size_t)n*H);
  ho[0] = pk.i4[0]; ho[1] = pk.i4[1];
  float ss = 0.f, sd = 0.f;
  #pragma unroll
  for (int j = 0; j < H; ++j){ ss += h[j]*sas[j]; sd += h[j]*sad[j]; }
  asn[n] = ss; adn[n] = sd;
}

// ---- BN sum/sumsq: per-block partials, zero global atomics ----
__global__ __launch_bounds__(TPB) void k_stats(const float* __restrict__ B,
    float* __restrict__ partial, int N){
  __shared__ float lds[4][32];
  int t = threadIdx.x;
  int n = blockIdx.x*TPB + t;
  float v[H];
  if (n < N){
    const float4* br = (const float4*)(B + (size_t)n*H);
    float4 a0 = br[0], a1 = br[1], a2 = br[2], a3 = br[3];
    v[0]=a0.x; v[1]=a0.y; v[2]=a0.z; v[3]=a0.w;
    v[4]=a1.x; v[5]=a1.y; v[6]=a1.z; v[7]=a1.w;
    v[8]=a2.x; v[9]=a2.y; v[10]=a2.z; v[11]=a2.w;
    v[12]=a3.x; v[13]=a3.y; v[14]=a3.z; v[15]=a3.w;
  } else {
    #pragma unroll
    for (int f = 0; f < H; ++f) v[f] = 0.f;
  }
  float s[H], q[H];
  #pragma unroll
  for (int f = 0; f < H; ++f){ s[f] = v[f]; q[f] = v[f]*v[f]; }
  for (int m = 1; m < 64; m <<= 1){
    #pragma unroll
    for (int f = 0; f < H; ++f){
      s[f] += __shfl_xor(s[f], m);
      q[f] += __shfl_xor(q[f], m);
    }
  }
  int wave = t >> 6, lane = t & 63;
  if (lane == 0){
    #pragma unroll
    for (int f = 0; f < H; ++f){ lds[wave][f] = s[f]; lds[wave][H+f] = q[f]; }
  }
  __syncthreads();
  if (t < 32)
    partial[(size_t)blockIdx.x*32 + t] = lds[0][t] + lds[1][t] + lds[2][t] + lds[3][t];
}

// ---- final BN reduction over block partials + scale/shift ----
__global__ __launch_bounds__(256) void k_bnprep(const float* __restrict__ partial, int nb,
    const float* __restrict__ gamma, const float* __restrict__ beta,
    float* __restrict__ scale, float* __restrict__ shift, int N){
  __shared__ float red[256];
  __shared__ float tot[32];
  int t = threadIdx.x;
  int f = t & 31, c = t >> 5;        // 8 chunks x 32 features
  float s = 0.f;
  for (int b = c; b < nb; b += 8) s += partial[(size_t)b*32 + f];
  red[c*32 + f] = s;
  __syncthreads();
  if (t < 32){
    float S = 0.f;
    #pragma unroll
    for (int cc = 0; cc < 8; ++cc) S += red[cc*32 + t];
    tot[t] = S;
  }
  __syncthreads();
  if (t < H){
    float inv = 1.f / (float)N;
    float mu  = tot[t] * inv;
    float var = tot[H+t] * inv - mu*mu;
    float sc  = gamma[t] * rsqrtf(var + 1e-5f);
    scale[t] = sc;
    shift[t] = beta[t] - mu*sc;
  }
}

// ---- layer-2 node transform: BN + h = xn @ W2 (stored fp16) + alphas ----
__global__ __launch_bounds__(TPB) void k_node2(const float* __restrict__ Bin, const float* __restrict__ scale,
    const float* __restrict__ shift, const float* __restrict__ W,
    const float* __restrict__ av_s, const float* __restrict__ av_d,
    __half* __restrict__ hout, float* __restrict__ asn, float* __restrict__ adn, int N){
  __shared__ float sW[H*H];
  __shared__ float ssc[H], ssh[H], sas[H], sad[H];
  int t = threadIdx.x;
  if (t < H*H) sW[t] = W[t];
  if (t < H){ ssc[t] = scale[t]; ssh[t] = shift[t]; sas[t] = av_s[t]; sad[t] = av_d[t]; }
  __syncthreads();
  int n = blockIdx.x*TPB + t;
  if (n >= N) return;
  const float4* br = (const float4*)(Bin + (size_t)n*H);
  float4 a0 = br[0], a1 = br[1], a2 = br[2], a3 = br[3];
  float xn[H] = {a0.x,a0.y,a0.z,a0.w, a1.x,a1.y,a1.z,a1.w,
                 a2.x,a2.y,a2.z,a2.w, a3.x,a3.y,a3.z,a3.w};
  #pragma unroll
  for (int f = 0; f < H; ++f) xn[f] = xn[f]*ssc[f] + ssh[f];
  float h[H];
  #pragma unroll
  for (int j = 0; j < H; ++j) h[j] = 0.f;
  #pragma unroll
  for (int k = 0; k < H; ++k){
    float xv = xn[k];
    #pragma unroll
    for (int j = 0; j < H; ++j) h[j] += xv * sW[k*H+j];
  }
  union { int4 i4[2]; __half hh[H]; } pk;
  #pragma unroll
  for (int j = 0; j < H; ++j) pk.hh[j] = __float2half_rn(h[j]);
  int4* ho = (int4*)(hout + (size_t)n*H);
  ho[0] = pk.i4[0]; ho[1] = pk.i4[1];
  float ss = 0.f, sd = 0.f;
  #pragma unroll
  for (int j = 0; j < H; ++j){ ss += h[j]*sas[j]; sd += h[j]*sad[j]; }
  asn[n] = ss; adn[n] = sd;
}

// ---- mean-pool: LDS per-block segmented partials (batch sorted -> block spans
//      a contiguous graph range, typ. 2-3). One global atomicAdd per
//      (touched graph, feature) per block instead of per-lane atomics. ----
__global__ __launch_bounds__(TPB) void k_pool(const float* __restrict__ B,
    const int* __restrict__ batch, float* __restrict__ pooled, float* __restrict__ gcnt, int N){
  __shared__ float acc[PSPAN*H];
  __shared__ float cacc[PSPAN];
  __shared__ int sg[2];
  int t = threadIdx.x;
  int n0 = blockIdx.x*TPB;
  int n = n0 + t;
  if (t == 0){
    sg[0] = batch[n0];
    int n1 = min(n0 + TPB - 1, N - 1);
    sg[1] = batch[n1];
  }
  __syncthreads();
  int gmin = sg[0];
  int span = sg[1] - gmin + 1;
  bool fits = (span <= PSPAN);        // block-uniform
  if (fits){
    for (int i = t; i < span*H; i += TPB) acc[i] = 0.f;
    for (int i = t; i < span; i += TPB) cacc[i] = 0.f;
    __syncthreads();
  }
  int lane = t & 63;
  bool valid = n < N;
  int g = valid ? batch[n] : -1;
  float v[H];
  if (valid){
    const float4* br = (const float4*)(B + (size_t)n*H);
    float4 a0 = br[0], a1 = br[1], a2 = br[2], a3 = br[3];
    v[0]=a0.x; v[1]=a0.y; v[2]=a0.z; v[3]=a0.w;
    v[4]=a1.x; v[5]=a1.y; v[6]=a1.z; v[7]=a1.w;
    v[8]=a2.x; v[9]=a2.y; v[10]=a2.z; v[11]=a2.w;
    v[12]=a3.x; v[13]=a3.y; v[14]=a3.z; v[15]=a3.w;
  } else {
    #pragma unroll
    for (int f = 0; f < H; ++f) v[f] = 0.f;
  }
  int g0 = __shfl(g, 0);
  bool allsame = __all(valid && g == g0);
  if (fits){
    if (allsame){
      float s[H];
      #pragma unroll
      for (int f = 0; f < H; ++f) s[f] = v[f];
      for (int m = 1; m < 64; m <<= 1){
        #pragma unroll
        for (int f = 0; f < H; ++f) s[f] += __shfl_xor(s[f], m);
      }
      if (lane == 0){
        float* p = acc + (g0 - gmin)*H;
        #pragma unroll
        for (int f = 0; f < H; ++f) atomicAdd(&p[f], s[f]);
        atomicAdd(&cacc[g0 - gmin], 64.f);
      }
    } else if (valid){
      float* p = acc + (g - gmin)*H;
      #pragma unroll
      for (int f = 0; f < H; ++f) atomicAdd(&p[f], v[f]);
      atomicAdd(&cacc[g - gmin], 1.f);
    }
    __syncthreads();
    // flush block partials: ~span*17 global atomics, low per-address multiplicity
    for (int i = t; i < span*H; i += TPB){
      float a = acc[i];
      if (a != 0.f) atomicAdd(&pooled[(size_t)gmin*H + i], a);
    }
    for (int i = t; i < span; i += TPB){
      float c = cacc[i];
      if (c != 0.f) atomicAdd(&gcnt[gmin + i], c);
    }
  } else {
    // safety fallback (never expected): direct global atomics
    if (allsame){
      float s[H];
      #pragma unroll
      for (int f = 0; f < H; ++f) s[f] = v[f];
      for (int m = 1; m < 64; m <<= 1){
        #pragma unroll
        for (int f = 0; f < H; ++f) s[f] += __shfl_xor(s[f], m);
      }
      if (lane == 0){
        float* p = pooled + (size_t)g0*H;
        #pragma unroll
        for (int f = 0; f < H; ++f) atomicAdd(&p[f], s[f]);
        atomicAdd(&gcnt[g0], 64.f);
      }
    } else if (valid){
      float* p = pooled + (size_t)g*H;
      #pragma unroll
      for (int f = 0; f < H; ++f) atomicAdd(&p[f], v[f]);
      atomicAdd(&gcnt[g], 1.f);
    }
  }
}

// ---- D2RL head: one block of 512 threads (one per graph) ----
__device__ void block_stats16(const float* v, float* mu, float* rs,
                              float* wsum, float* wsq, int G){
  float s[H], q[H];
  #pragma unroll
  for (int f = 0; f < H; ++f){ s[f] = v[f]; q[f] = v[f]*v[f]; }
  for (int m = 1; m < 64; m <<= 1){
    #pragma unroll
    for (int f = 0; f < H; ++f){
      s[f] += __shfl_xor(s[f], m);
      q[f] += __shfl_xor(q[f], m);
    }
  }
  int wave = threadIdx.x >> 6, lane = threadIdx.x & 63;
  if (lane == 0){
    #pragma unroll
    for (int f = 0; f < H; ++f){ wsum[wave*H+f] = s[f]; wsq[wave*H+f] = q[f]; }
  }
  __syncthreads();
  int t = threadIdx.x;
  if (t < H){
    float S = 0.f, Q = 0.f;
    for (int w = 0; w < 8; ++w){ S += wsum[w*H+t]; Q += wsq[w*H+t]; }
    float m_ = S / (float)G;
    float var = Q / (float)G - m_*m_;
    mu[t] = m_;
    rs[t] = rsqrtf(var + 1e-5f);
  }
  __syncthreads();
}

__global__ __launch_bounds__(512) void k_head(const float* __restrict__ pooled, const float* __restrict__ gcnt,
    const float* __restrict__ g1, const float* __restrict__ be1,
    const float* __restrict__ Wl1, const float* __restrict__ bl1,
    const float* __restrict__ g2, const float* __restrict__ be2,
    const float* __restrict__ Wl2, const float* __restrict__ bl2,
    const float* __restrict__ g3, const float* __restrict__ be3,
    const float* __restrict__ Wl3, const float* __restrict__ bl3,
    const float* __restrict__ Wo, const float* __restrict__ bo,
    float* __restrict__ out, int G){
  __shared__ float wsum[8*H], wsq[8*H];
  __shared__ float pmu[H], prs[H], smu[H], srs[H];
  int g = threadIdx.x;
  float p[H];
  if (g < G){
    float c = fmaxf(gcnt[g], 1.f);
    #pragma unroll
    for (int f = 0; f < H; ++f) p[f] = pooled[(size_t)g*H+f] / c;
  } else {
    #pragma unroll
    for (int f = 0; f < H; ++f) p[f] = 0.f;
  }
  block_stats16(p, pmu, prs, wsum, wsq, G);
  float xn[H], z[H];
  #pragma unroll
  for (int f = 0; f < H; ++f) xn[f] = g1[f]*(p[f]-pmu[f])*prs[f] + be1[f];
  #pragma unroll
  for (int j = 0; j < H; ++j) z[j] = bl1[j];
  for (int k = 0; k < H; ++k){
    float xv = xn[k];
    #pragma unroll
    for (int j = 0; j < H; ++j) z[j] += xv * Wl1[k*H+j];
  }
  #pragma unroll
  for (int j = 0; j < H; ++j) z[j] = fmaxf(z[j], 0.f);
  block_stats16(z, smu, srs, wsum, wsq, G);
  float x2[2*H], z2[H];
  #pragma unroll
  for (int f = 0; f < H; ++f){
    x2[f]   = g2[f]  *(z[f]-smu[f])*srs[f] + be2[f];
    x2[H+f] = g2[H+f]*(p[f]-pmu[f])*prs[f] + be2[H+f];
  }
  #pragma unroll
  for (int j = 0; j < H; ++j) z2[j] = bl2[j];
  for (int k = 0; k < 2*H; ++k){
    float xv = x2[k];
    #pragma unroll
    for (int j = 0; j < H; ++j) z2[j] += xv * Wl2[k*H+j];
  }
  #pragma unroll
  for (int j = 0; j < H; ++j) z2[j] = fmaxf(z2[j], 0.f);
  block_stats16(z2, smu, srs, wsum, wsq, G);
  float x3[2*H], z3[H];
  #pragma unroll
  for (int f = 0; f < H; ++f){
    x3[f]   = g3[f]  *(z2[f]-smu[f])*srs[f] + be3[f];
    x3[H+f] = g3[H+f]*(p[f]-pmu[f])*prs[f] + be3[H+f];
  }
  #pragma unroll
  for (int j = 0; j < H; ++j) z3[j] = bl3[j];
  for (int k = 0; k < 2*H; ++k){
    float xv = x3[k];
    #pragma unroll
    for (int j = 0; j < H; ++j) z3[j] += xv * Wl3[k*H+j];
  }
  #pragma unroll
  for (int j = 0; j < H; ++j) z3[j] = fmaxf(z3[j], 0.f);
  if (g < G){
    float o = bo[0];
    #pragma unroll
    for (int j = 0; j < H; ++j) o += z3[j]*Wo[j];
    out[g] = o;
  }
}

extern "C" void kernel_launch(void* const* d_in, const int* in_sizes, int n_in,
                              void* d_out, int out_size, void* d_ws, size_t ws_size,
                              hipStream_t stream) {
  const float* x     = (const float*)d_in[0];
  const int*   ei    = (const int*)d_in[1];
  const float* attr  = (const float*)d_in[2];
  const int*   batch = (const int*)d_in[3];
  const float* W1  = (const float*)d_in[4];
  const float* We1 = (const float*)d_in[5];
  const float* as1 = (const float*)d_in[6];
  const float* ad1 = (const float*)d_in[7];
  const float* ae1 = (const float*)d_in[8];
  const float* b1  = (const float*)d_in[9];
  const float* bn1g = (const float*)d_in[10];
  const float* bn1b = (const float*)d_in[11];
  const float* W2  = (const float*)d_in[12];
  const float* We2 = (const float*)d_in[13];
  const float* as2 = (const float*)d_in[14];
  const float* ad2 = (const float*)d_in[15];
  const float* ae2 = (const float*)d_in[16];
  const float* b2  = (const float*)d_in[17];
  const float* bnl1g = (const float*)d_in[18];
  const float* bnl1b = (const float*)d_in[19];
  const float* Wl1 = (const float*)d_in[20];
  const float* bl1 = (const float*)d_in[21];
  const float* bnl2g = (const float*)d_in[22];
  const float* bnl2b = (const float*)d_in[23];
  const float* Wl2 = (const float*)d_in[24];
  const float* bl2 = (const float*)d_in[25];
  const float* bnl3g = (const float*)d_in[26];
  const float* bnl3b = (const float*)d_in[27];
  const float* Wl3 = (const float*)d_in[28];
  const float* bl3 = (const float*)d_in[29];
  const float* Wo  = (const float*)d_in[30];
  const float* bo  = (const float*)d_in[31];

  int N = in_sizes[0] / NF;
  int E = in_sizes[1] / 2;
  int G = out_size;
  const int* srcp = ei;
  const int* dstp = ei + E;

  int B     = (N + 63) >> 6;                         // 64-node buckets (2344)
  int M     = B * NB;                                // count-matrix size (600064)
  int chunk = (E + NB - 1) / NB;                     // edges per binning block (18750)
  int nbN   = (N + TPB - 1)/TPB;
  int nbS   = (M + SBLK*SITEMS - 1)/(SBLK*SITEMS);   // scan blocks (147 <= 256)

  // ---- workspace layout (rec persists through both GAT layers; no aliasing) ----
  char* wsb = (char*)d_ws;
  int2*  rec = (int2*)wsb;                           // 8B * E
  char* p = wsb + (size_t)8*E;
  __half* A = (__half*)p;     p += (size_t)2*H*N;    // h table (fp16, 4.8 MB)
  float* Bv  = (float*)p;     p += (size_t)16*N*4;   // layer output (fp32)
  float* asn = (float*)p;     p += (size_t)N*4;
  float* adn = (float*)p;     p += (size_t)N*4;
  int*   cnt     = (int*)p;   p += (size_t)4*M;      // per-(bucket,block) counts -> bases
  int*   cntT    = (int*)p;   p += (size_t)4*M;      // transposed bases [blk][b]
  int*   bbase   = (int*)p;   p += (size_t)4*(B+1);
  int*   part    = (int*)p;   p += (size_t)4*256;
  float* par     = (float*)p; p += 4*64;             // [0..3]=wp [4..19]=scale [20..35]=shift
  float* pooled  = (float*)p; p += (size_t)4*G*H;
  float* gcnt    = (float*)p; p += (size_t)4*G;
  float* partial = (float*)p; p += (size_t)4*nbN*32;

  float* bnscale = par + 4;
  float* bnshift = par + 20;

  // zero-init (ws is re-poisoned 0xAA before every launch)
  hipMemsetAsync(pooled, 0, (size_t)(G*H + G)*sizeof(float), stream);

  k_prep<<<1, 64, 0, stream>>>(We1, ae1, We2, ae2, par);

  // ---- binning: two-pass exclusive-range, 8B records, no global atomics ----
  k_bcount<<<NB, BTPB, 0, stream>>>(dstp, cnt, E, B, chunk);
  k_scan1<<<nbS, SBLK, 0, stream>>>(cnt, part, M);
  k_scan2<<<1, SBLK, 0, stream>>>(part, nbS, bbase, B, E);
  k_scan3<<<nbS, SBLK, 0, stream>>>(cnt, part, bbase, cntT, B, M);
  k_bwrite<<<NB, BTPB, 0, stream>>>(srcp, dstp, attr, par, cntT, rec, E, B, chunk);

  // ---- layer 1 ----
  k_node1<<<nbN, TPB, 0, stream>>>(x, W1, as1, ad1, A, asn, adn, N);
  k_gatf<0><<<B, GTPB, 0, stream>>>(rec, bbase, asn, adn, A, b1, Bv, N);
  k_stats<<<nbN, TPB, 0, stream>>>(Bv, partial, N);
  k_bnprep<<<1, 256, 0, stream>>>(partial, nbN, bn1g, bn1b, bnscale, bnshift, N);

  // ---- layer 2 ----
  k_node2<<<nbN, TPB, 0, stream>>>(Bv, bnscale, bnshift, W2, as2, ad2, A, asn, adn, N);
  k_gatf<1><<<B, GTPB, 0, stream>>>(rec, bbase, asn, adn, A, b2, Bv, N);

  // ---- pool + head ----
  k_pool<<<nbN, TPB, 0, stream>>>(Bv, batch, pooled, gcnt, N);
  k_head<<<1, 512, 0, stream>>>(pooled, gcnt, bnl1g, bnl1b, Wl1, bl1, bnl2g, bnl2b, Wl2, bl2,
                                bnl3g, bnl3b, Wl3, bl3, Wo, bo, (float*)d_out, G);
}

// Round 11
// 468.317 us; speedup vs baseline: 1.0748x; 1.0360x over previous
//
#include <hip/hip_runtime.h>
#include <hip/hip_fp16.h>
#include <math.h>

#define H 16
#define NF 64
#define TPB 256
#define NB 256        // binning blocks (1/CU)
#define NBSHIFT 8     // log2(NB)
#define BTPB 1024     // binning threads per block
#define GTPB 512      // gat threads per block (64 nodes x 8 lanes)
#define NSHIFT 6      // bucket = 64 consecutive dst nodes
#define MAXB 2560     // LDS counter capacity (B = ceil(150000/64) = 2344)
#define SBLK 256
#define SITEMS 16     // scan: 4096/block; M=2344*256=600064 -> 147 blocks <= 256
#define SRCMASK 0x3FFFF
#define CAP 2432      // bucket record capacity (mean 2048, sigma~45 -> +8.5σ);
                      // 2x int2[CAP] = 38KB LDS -> 4 blocks/CU (was 3072 -> 2)
#define STAGE_CAP 18752  // >= chunk = ceil(E/NB) = 18750
#define PSPAN 96      // max graphs a 256-node block can span (typ. 2-3)

__device__ __forceinline__ float lrelu(float v){ return v > 0.f ? v : 0.2f*v; }

// ---- derived edge-attention weights: par[0..1] = We1@ae1, par[2..3] = We2@ae2 ----
__global__ void k_prep(const float* __restrict__ We1, const float* __restrict__ ae1,
                       const float* __restrict__ We2, const float* __restrict__ ae2,
                       float* __restrict__ params){
  int t = threadIdx.x;
  if (t < 4){
    const float* We = (t < 2) ? We1 : We2;
    const float* ae = (t < 2) ? ae1 : ae2;
    int r = t & 1;
    float s = 0.f;
    for (int c = 0; c < H; ++c) s += We[r*H + c] * ae[c];
    params[t] = s;
  }
}

// ---- pass 1: per-(bucket, block) histogram in LDS ----
__global__ __launch_bounds__(BTPB) void k_bcount(const int* __restrict__ dst,
    int* __restrict__ cnt, int E, int B, int chunk){
  __shared__ int lcnt[MAXB];
  int blk = blockIdx.x, t = threadIdx.x;
  for (int i = t; i < B; i += BTPB) lcnt[i] = 0;
  __syncthreads();
  int e0 = blk*chunk, e1 = min(E, e0 + chunk);
  for (int e = e0 + t; e < e1; e += BTPB){
    int d = __builtin_nontemporal_load(dst + e);   // NT: don't pollute L2
    atomicAdd(&lcnt[d >> NSHIFT], 1);
  }
  __syncthreads();
  for (int i = t; i < B; i += BTPB) cnt[(size_t)i*NB + blk] = lcnt[i];
}

// ---- scan of the count matrix (bucket-major) -> exclusive ranges ----
__global__ __launch_bounds__(SBLK) void k_scan1(const int* __restrict__ cnt,
    int* __restrict__ part, int M){
  __shared__ int red[SBLK];
  int base = blockIdx.x*SBLK*SITEMS;
  int t = threadIdx.x;
  int s = 0;
  for (int i = 0; i < SITEMS; ++i){
    int idx = base + t*SITEMS + i;
    s += (idx < M) ? cnt[idx] : 0;
  }
  red[t] = s; __syncthreads();
  for (int off = SBLK/2; off > 0; off >>= 1){
    if (t < off) red[t] += red[t+off];
    __syncthreads();
  }
  if (t == 0) part[blockIdx.x] = red[0];
}

__global__ __launch_bounds__(SBLK) void k_scan2(int* __restrict__ part, int nb,
    int* __restrict__ bbase, int B, int E){
  __shared__ int sh[SBLK];
  int t = threadIdx.x;
  int v = (t < nb) ? part[t] : 0;
  sh[t] = v; __syncthreads();
  for (int off = 1; off < SBLK; off <<= 1){
    int add = (t >= off) ? sh[t-off] : 0;
    __syncthreads();
    sh[t] += add;
    __syncthreads();
  }
  if (t < nb) part[t] = sh[t] - v;   // exclusive block offsets
  if (t == 0) bbase[B] = E;
}

// also emits the TRANSPOSED base matrix cntT[blk*B + b] so k_bwrite can read
// its column as two sequential rows (count = next base - base).
__global__ __launch_bounds__(SBLK) void k_scan3(int* __restrict__ cnt,
    const int* __restrict__ part, int* __restrict__ bbase,
    int* __restrict__ cntT, int B, int M){
  __shared__ int sh[SBLK];
  int base = blockIdx.x*SBLK*SITEMS;
  int t = threadIdx.x;
  int loc[SITEMS]; int s = 0;
  for (int i = 0; i < SITEMS; ++i){
    int idx = base + t*SITEMS + i;
    loc[i] = s;
    s += (idx < M) ? cnt[idx] : 0;
  }
  sh[t] = s; __syncthreads();
  for (int off = 1; off < SBLK; off <<= 1){
    int add = (t >= off) ? sh[t-off] : 0;
    __syncthreads();
    sh[t] += add;
    __syncthreads();
  }
  int toff = sh[t] - s + part[blockIdx.x];
  for (int i = 0; i < SITEMS; ++i){
    int idx = base + t*SITEMS + i;
    if (idx < M){
      int excl = toff + loc[i];
      cnt[idx] = excl;                               // in-place per-(bucket,block) base
      cntT[(size_t)(idx & (NB-1))*B + (idx >> NBSHIFT)] = excl;
      if ((idx & (NB-1)) == 0) bbase[idx / NB] = excl;
    }
  }
}

// ---- pass 2: LDS counting-sort of the block's chunk, then BURST write-out.
//      Each (bucket,block) segment of rec is written once, contiguously, by
//      consecutive lanes -> no partial-line thrash. Local per-bucket counts are
//      derived from consecutive exclusive bases in cntT (no histogram pass). ----
__global__ __launch_bounds__(BTPB) void k_bwrite(const int* __restrict__ src,
    const int* __restrict__ dst, const float* __restrict__ attr, const float* __restrict__ wp,
    const int* __restrict__ cntT, int2* __restrict__ rec, int E, int B, int chunk){
  __shared__ int2 stage[STAGE_CAP];
  __shared__ int ex[MAXB];
  __shared__ int wsum[16];
  int blk = blockIdx.x, t = threadIdx.x;
  const int* row0 = cntT + (size_t)blk*B;
  const int* row1 = cntT + (size_t)(blk+1)*B;
  // local exclusive scan of this block's per-bucket counts (ITEMS=3, 3072 >= B)
  {
    int v[3]; int s = 0;
    int base3 = t*3;
    #pragma unroll
    for (int i = 0; i < 3; ++i){
      int idx = base3 + i;
      int c = 0;
      if (idx < B){
        int g0 = row0[idx];
        int g1;
        if (blk < NB-1)      g1 = row1[idx];
        else if (idx < B-1)  g1 = cntT[idx+1];   // row 0 of next bucket
        else                 g1 = E;
        c = g1 - g0;
      }
      v[i] = c; s += c;
    }
    int lane = t & 63, wave = t >> 6;
    int x = s;
    for (int o = 1; o < 64; o <<= 1){
      int y = __shfl_up(x, o);
      if (lane >= o) x += y;
    }
    if (lane == 63) wsum[wave] = x;
    __syncthreads();
    if (t < 16){
      int w = wsum[t];
      int xx = w;
      for (int o = 1; o < 16; o <<= 1){
        int y = __shfl_up(xx, o);
        if (t >= o) xx += y;
      }
      wsum[t] = xx - w;   // exclusive wave base
    }
    __syncthreads();
    int run = wsum[wave] + (x - s);
    #pragma unroll
    for (int i = 0; i < 3; ++i){
      int idx = base3 + i;
      if (idx < B) ex[idx] = run;
      run += v[i];
    }
  }
  __syncthreads();
  // single edge pass: compute record, scatter into LDS at sorted position
  float w0 = wp[0], w1 = wp[1], w2 = wp[2], w3 = wp[3];
  int e0 = blk*chunk, e1 = min(E, e0 + chunk);
  for (int e = e0 + t; e < e1; e += BTPB){
    int d = __builtin_nontemporal_load(dst + e);
    int s = __builtin_nontemporal_load(src + e);
    union { double dd; float2 ff; } u;
    u.dd = __builtin_nontemporal_load((const double*)attr + e);
    float2 a = u.ff;
    int b = d >> NSHIFT;
    __half h1 = __float2half_rn(a.x*w0 + a.y*w1);
    __half h2 = __float2half_rn(a.x*w2 + a.y*w3);
    unsigned uu = (unsigned)__half_as_ushort(h1) | ((unsigned)__half_as_ushort(h2) << 16);
    int pos = atomicAdd(&ex[b], 1);
    stage[pos] = make_int2(s | ((d & 63) << 18), (int)uu);
  }
  __syncthreads();
  // burst write-out: 8 lanes per bucket; segments are contiguous in rec
  int grp = t >> 3, l8 = t & 7;
  for (int b = grp; b < B; b += (BTPB/8)){
    int start = (b == 0) ? 0 : ex[b-1];   // ex advanced by count during scatter
    int end = ex[b];
    if (start == end) continue;
    int gb = row0[b];
    for (int j = start + l8; j < end; j += 8)
      rec[(size_t)gb + (j - start)] = stage[j];
  }
}

// ---- fused GAT: per-bucket LDS RECORD-sort + softmax aggregate ----
// 512 threads = 64 nodes x 8 lanes (lane = feature PAIR, half2 loads).
// CAP=2432 keeps LDS under 40KB -> 4 blocks/CU (32 waves) for latency hiding.
template<int SEL>
__global__ __launch_bounds__(GTPB) void k_gatf(const int2* __restrict__ rec,
    const int* __restrict__ bbase, const float* __restrict__ asn, const float* __restrict__ adn,
    const __half* __restrict__ h, const float* __restrict__ bias,
    float* __restrict__ out, int N){
  __shared__ int2 stage[CAP];    // raw: {src|ld<<18, w bits}
  __shared__ int2 sorted[CAP];   // sorted by ld
  __shared__ int lcnt[64], lcur[64], sr[2];
  __shared__ float sadn[64], sbias[H], sdacc[64];
  int b = blockIdx.x, t = threadIdx.x;
  int node0 = b << NSHIFT;
  if (t < 2) sr[t] = bbase[b + t];
  if (t < 64){
    lcnt[t] = 0;
    sdacc[t] = 0.f;
    int nn = node0 + t;
    sadn[t] = (nn < N) ? adn[nn] : 0.f;
  }
  if (t >= 64 && t < 64 + H) sbias[t - 64] = bias[t - 64];
  __syncthreads();
  int r0 = sr[0], cnt = sr[1] - r0;
  // phase A: load rec (NT), decode, asn gather, exp weight, histogram + sd
  for (int i = t; i < cnt; i += GTPB){
    long long raw = __builtin_nontemporal_load((const long long*)(rec + r0 + i));
    int rx = (int)(unsigned)(raw & 0xFFFFFFFFll);
    unsigned u = (unsigned)((unsigned long long)raw >> 32);
    int ld = ((unsigned)rx) >> 18;
    float d = __half2float(__ushort_as_half((unsigned short)(SEL ? (u >> 16) : (u & 0xFFFFu))));
    float w = __expf(lrelu(asn[rx & SRCMASK] + sadn[ld] + d));
    stage[i] = make_int2(rx, __float_as_int(w));
    atomicAdd(&lcnt[ld], 1);
    atomicAdd(&sdacc[ld], d);
  }
  __syncthreads();
  // exclusive scan over 64 node counters (wave 0)
  if (t < 64){
    int v = lcnt[t];
    int x = v;
    for (int o = 1; o < 64; o <<= 1){
      int y = __shfl_up(x, o);
      if (t >= o) x += y;
    }
    lcur[t] = x - v;
  }
  __syncthreads();
  // phase C: pure LDS scatter of full records to sorted positions
  for (int i = t; i < cnt; i += GTPB){
    int2 r = stage[i];
    sorted[atomicAdd(&lcur[((unsigned)r.x) >> 18], 1)] = r;
  }
  __syncthreads();
  int nl = t >> 3, l2 = t & 7;     // node, feature-pair lane
  int n = node0 + nl;
  if (n >= N) return;
  const __half2* h2 = (const __half2*)h;
  float b0 = sbias[2*l2], b1 = sbias[2*l2 + 1];
  int deg = lcnt[nl];
  int s0 = lcur[nl] - deg;          // lcur advanced by deg during scatter
  float den = 0.f, acc0 = 0.f, acc1 = 0.f;
  for (int j = 0; j < deg; ++j){
    int2 r = sorted[s0 + j];
    float w = __int_as_float(r.y);
    float2 f = __half22float2(h2[(size_t)(r.x & SRCMASK)*8 + l2]);
    den += w;
    acc0 += w * f.x;
    acc1 += w * f.y;
  }
  // self-loop: edge_attr = mean of incoming attr -> dot = mean of incoming dots
  float lael = sdacc[nl] / fmaxf((float)deg, 1.f);
  float wl = __expf(lrelu(asn[n] + sadn[nl] + lael));
  float2 fs = __half22float2(h2[(size_t)n*8 + l2]);
  den += wl;
  acc0 += wl * fs.x;
  acc1 += wl * fs.y;
  float inv = 1.f / (den + 1e-16f);
  ((float2*)out)[(size_t)n*8 + l2] =
      make_float2(fmaxf(acc0*inv + b0, 0.f), fmaxf(acc1*inv + b1, 0.f));
}

// ---- layer-1 node transform: h = x @ W1 (stored fp16), alpha_src/dst (fp32) ----
__global__ __launch_bounds__(TPB) void k_node1(const float* __restrict__ x, const float* __restrict__ W,
    const float* __restrict__ av_s, const float* __restrict__ av_d,
    __half* __restrict__ hout, float* __restrict__ asn, float* __restrict__ adn, int N){
  __shared__ float sW[NF*H];
  __shared__ float sas[H], sad[H];
  int t = threadIdx.x;
  for (int i = t; i < NF*H; i += TPB) sW[i] = W[i];
  if (t < H){ sas[t] = av_s[t]; sad[t] = av_d[t]; }
  __syncthreads();
  int n = blockIdx.x*TPB + t;
  if (n >= N) return;
  float h[H];
  #pragma unroll
  for (int j = 0; j < H; ++j) h[j] = 0.f;
  const float4* xr = (const float4*)(x + (size_t)n*NF);
  #pragma unroll
  for (int k4 = 0; k4 < NF/4; ++k4){
    float4 xv = xr[k4];
    #pragma unroll
    for (int j = 0; j < H; ++j){
      h[j] += xv.x*sW[(4*k4+0)*H+j] + xv.y*sW[(4*k4+1)*H+j]
            + xv.z*sW[(4*k4+2)*H+j] + xv.w*sW[(4*k4+3)*H+j];
    }
  }
  union { int4 i4[2]; __half hh[H]; } pk;
  #pragma unroll
  for (int j = 0; j < H; ++j) pk.hh[j] = __float2half_rn(h[j]);
  int4* ho = (int4*)(hout + (size_t)n*H);
  ho[0] = pk.i4[0]; ho[1] = pk.i4[1];
  float ss = 0.f, sd = 0.f;
  #pragma unroll
  for (int j = 0; j < H; ++j){ ss += h[j]*sas[j]; sd += h[j]*sad[j]; }
  asn[n] = ss; adn[n] = sd;
}

// ---- BN sum/sumsq: per-block partials, zero global atomics ----
__global__ __launch_bounds__(TPB) void k_stats(const float* __restrict__ B,
    float* __restrict__ partial, int N){
  __shared__ float lds[4][32];
  int t = threadIdx.x;
  int n = blockIdx.x*TPB + t;
  float v[H];
  if (n < N){
    const float4* br = (const float4*)(B + (size_t)n*H);
    float4 a0 = br[0], a1 = br[1], a2 = br[2], a3 = br[3];
    v[0]=a0.x; v[1]=a0.y; v[2]=a0.z; v[3]=a0.w;
    v[4]=a1.x; v[5]=a1.y; v[6]=a1.z; v[7]=a1.w;
    v[8]=a2.x; v[9]=a2.y; v[10]=a2.z; v[11]=a2.w;
    v[12]=a3.x; v[13]=a3.y; v[14]=a3.z; v[15]=a3.w;
  } else {
    #pragma unroll
    for (int f = 0; f < H; ++f) v[f] = 0.f;
  }
  float s[H], q[H];
  #pragma unroll
  for (int f = 0; f < H; ++f){ s[f] = v[f]; q[f] = v[f]*v[f]; }
  for (int m = 1; m < 64; m <<= 1){
    #pragma unroll
    for (int f = 0; f < H; ++f){
      s[f] += __shfl_xor(s[f], m);
      q[f] += __shfl_xor(q[f], m);
    }
  }
  int wave = t >> 6, lane = t & 63;
  if (lane == 0){
    #pragma unroll
    for (int f = 0; f < H; ++f){ lds[wave][f] = s[f]; lds[wave][H+f] = q[f]; }
  }
  __syncthreads();
  if (t < 32)
    partial[(size_t)blockIdx.x*32 + t] = lds[0][t] + lds[1][t] + lds[2][t] + lds[3][t];
}

// ---- final BN reduction over block partials + scale/shift ----
__global__ __launch_bounds__(256) void k_bnprep(const float* __restrict__ partial, int nb,
    const float* __restrict__ gamma, const float* __restrict__ beta,
    float* __restrict__ scale, float* __restrict__ shift, int N){
  __shared__ float red[256];
  __shared__ float tot[32];
  int t = threadIdx.x;
  int f = t & 31, c = t >> 5;        // 8 chunks x 32 features
  float s = 0.f;
  for (int b = c; b < nb; b += 8) s += partial[(size_t)b*32 + f];
  red[c*32 + f] = s;
  __syncthreads();
  if (t < 32){
    float S = 0.f;
    #pragma unroll
    for (int cc = 0; cc < 8; ++cc) S += red[cc*32 + t];
    tot[t] = S;
  }
  __syncthreads();
  if (t < H){
    float inv = 1.f / (float)N;
    float mu  = tot[t] * inv;
    float var = tot[H+t] * inv - mu*mu;
    float sc  = gamma[t] * rsqrtf(var + 1e-5f);
    scale[t] = sc;
    shift[t] = beta[t] - mu*sc;
  }
}

// ---- layer-2 node transform: BN + h = xn @ W2 (stored fp16) + alphas ----
__global__ __launch_bounds__(TPB) void k_node2(const float* __restrict__ Bin, const float* __restrict__ scale,
    const float* __restrict__ shift, const float* __restrict__ W,
    const float* __restrict__ av_s, const float* __restrict__ av_d,
    __half* __restrict__ hout, float* __restrict__ asn, float* __restrict__ adn, int N){
  __shared__ float sW[H*H];
  __shared__ float ssc[H], ssh[H], sas[H], sad[H];
  int t = threadIdx.x;
  if (t < H*H) sW[t] = W[t];
  if (t < H){ ssc[t] = scale[t]; ssh[t] = shift[t]; sas[t] = av_s[t]; sad[t] = av_d[t]; }
  __syncthreads();
  int n = blockIdx.x*TPB + t;
  if (n >= N) return;
  const float4* br = (const float4*)(Bin + (size_t)n*H);
  float4 a0 = br[0], a1 = br[1], a2 = br[2], a3 = br[3];
  float xn[H] = {a0.x,a0.y,a0.z,a0.w, a1.x,a1.y,a1.z,a1.w,
                 a2.x,a2.y,a2.z,a2.w, a3.x,a3.y,a3.z,a3.w};
  #pragma unroll
  for (int f = 0; f < H; ++f) xn[f] = xn[f]*ssc[f] + ssh[f];
  float h[H];
  #pragma unroll
  for (int j = 0; j < H; ++j) h[j] = 0.f;
  #pragma unroll
  for (int k = 0; k < H; ++k){
    float xv = xn[k];
    #pragma unroll
    for (int j = 0; j < H; ++j) h[j] += xv * sW[k*H+j];
  }
  union { int4 i4[2]; __half hh[H]; } pk;
  #pragma unroll
  for (int j = 0; j < H; ++j) pk.hh[j] = __float2half_rn(h[j]);
  int4* ho = (int4*)(hout + (size_t)n*H);
  ho[0] = pk.i4[0]; ho[1] = pk.i4[1];
  float ss = 0.f, sd = 0.f;
  #pragma unroll
  for (int j = 0; j < H; ++j){ ss += h[j]*sas[j]; sd += h[j]*sad[j]; }
  asn[n] = ss; adn[n] = sd;
}

// ---- mean-pool: LDS per-block segmented partials (batch sorted -> block spans
//      a contiguous graph range, typ. 2-3). One global atomicAdd per
//      (touched graph, feature) per block instead of per-lane atomics. ----
__global__ __launch_bounds__(TPB) void k_pool(const float* __restrict__ B,
    const int* __restrict__ batch, float* __restrict__ pooled, float* __restrict__ gcnt, int N){
  __shared__ float acc[PSPAN*H];
  __shared__ float cacc[PSPAN];
  __shared__ int sg[2];
  int t = threadIdx.x;
  int n0 = blockIdx.x*TPB;
  int n = n0 + t;
  if (t == 0){
    sg[0] = batch[n0];
    int n1 = min(n0 + TPB - 1, N - 1);
    sg[1] = batch[n1];
  }
  __syncthreads();
  int gmin = sg[0];
  int span = sg[1] - gmin + 1;
  bool fits = (span <= PSPAN);        // block-uniform
  if (fits){
    for (int i = t; i < span*H; i += TPB) acc[i] = 0.f;
    for (int i = t; i < span; i += TPB) cacc[i] = 0.f;
    __syncthreads();
  }
  int lane = t & 63;
  bool valid = n < N;
  int g = valid ? batch[n] : -1;
  float v[H];
  if (valid){
    const float4* br = (const float4*)(B + (size_t)n*H);
    float4 a0 = br[0], a1 = br[1], a2 = br[2], a3 = br[3];
    v[0]=a0.x; v[1]=a0.y; v[2]=a0.z; v[3]=a0.w;
    v[4]=a1.x; v[5]=a1.y; v[6]=a1.z; v[7]=a1.w;
    v[8]=a2.x; v[9]=a2.y; v[10]=a2.z; v[11]=a2.w;
    v[12]=a3.x; v[13]=a3.y; v[14]=a3.z; v[15]=a3.w;
  } else {
    #pragma unroll
    for (int f = 0; f < H; ++f) v[f] = 0.f;
  }
  int g0 = __shfl(g, 0);
  bool allsame = __all(valid && g == g0);
  if (fits){
    if (allsame){
      float s[H];
      #pragma unroll
      for (int f = 0; f < H; ++f) s[f] = v[f];
      for (int m = 1; m < 64; m <<= 1){
        #pragma unroll
        for (int f = 0; f < H; ++f) s[f] += __shfl_xor(s[f], m);
      }
      if (lane == 0){
        float* p = acc + (g0 - gmin)*H;
        #pragma unroll
        for (int f = 0; f < H; ++f) atomicAdd(&p[f], s[f]);
        atomicAdd(&cacc[g0 - gmin], 64.f);
      }
    } else if (valid){
      float* p = acc + (g - gmin)*H;
      #pragma unroll
      for (int f = 0; f < H; ++f) atomicAdd(&p[f], v[f]);
      atomicAdd(&cacc[g - gmin], 1.f);
    }
    __syncthreads();
    // flush block partials: ~span*17 global atomics, low per-address multiplicity
    for (int i = t; i < span*H; i += TPB){
      float a = acc[i];
      if (a != 0.f) atomicAdd(&pooled[(size_t)gmin*H + i], a);
    }
    for (int i = t; i < span; i += TPB){
      float c = cacc[i];
      if (c != 0.f) atomicAdd(&gcnt[gmin + i], c);
    }
  } else {
    // safety fallback (never expected): direct global atomics
    if (allsame){
      float s[H];
      #pragma unroll
      for (int f = 0; f < H; ++f) s[f] = v[f];
      for (int m = 1; m < 64; m <<= 1){
        #pragma unroll
        for (int f = 0; f < H; ++f) s[f] += __shfl_xor(s[f], m);
      }
      if (lane == 0){
        float* p = pooled + (size_t)g0*H;
        #pragma unroll
        for (int f = 0; f < H; ++f) atomicAdd(&p[f], s[f]);
        atomicAdd(&gcnt[g0], 64.f);
      }
    } else if (valid){
      float* p = pooled + (size_t)g*H;
      #pragma unroll
      for (int f = 0; f < H; ++f) atomicAdd(&p[f], v[f]);
      atomicAdd(&gcnt[g], 1.f);
    }
  }
}

// ---- D2RL head: one block of 512 threads (one per graph) ----
__device__ void block_stats16(const float* v, float* mu, float* rs,
                              float* wsum, float* wsq, int G){
  float s[H], q[H];
  #pragma unroll
  for (int f = 0; f < H; ++f){ s[f] = v[f]; q[f] = v[f]*v[f]; }
  for (int m = 1; m < 64; m <<= 1){
    #pragma unroll
    for (int f = 0; f < H; ++f){
      s[f] += __shfl_xor(s[f], m);
      q[f] += __shfl_xor(q[f], m);
    }
  }
  int wave = threadIdx.x >> 6, lane = threadIdx.x & 63;
  if (lane == 0){
    #pragma unroll
    for (int f = 0; f < H; ++f){ wsum[wave*H+f] = s[f]; wsq[wave*H+f] = q[f]; }
  }
  __syncthreads();
  int t = threadIdx.x;
  if (t < H){
    float S = 0.f, Q = 0.f;
    for (int w = 0; w < 8; ++w){ S += wsum[w*H+t]; Q += wsq[w*H+t]; }
    float m_ = S / (float)G;
    float var = Q / (float)G - m_*m_;
    mu[t] = m_;
    rs[t] = rsqrtf(var + 1e-5f);
  }
  __syncthreads();
}

__global__ __launch_bounds__(512) void k_head(const float* __restrict__ pooled, const float* __restrict__ gcnt,
    const float* __restrict__ g1, const float* __restrict__ be1,
    const float* __restrict__ Wl1, const float* __restrict__ bl1,
    const float* __restrict__ g2, const float* __restrict__ be2,
    const float* __restrict__ Wl2, const float* __restrict__ bl2,
    const float* __restrict__ g3, const float* __restrict__ be3,
    const float* __restrict__ Wl3, const float* __restrict__ bl3,
    const float* __restrict__ Wo, const float* __restrict__ bo,
    float* __restrict__ out, int G){
  __shared__ float wsum[8*H], wsq[8*H];
  __shared__ float pmu[H], prs[H], smu[H], srs[H];
  int g = threadIdx.x;
  float p[H];
  if (g < G){
    float c = fmaxf(gcnt[g], 1.f);
    #pragma unroll
    for (int f = 0; f < H; ++f) p[f] = pooled[(size_t)g*H+f] / c;
  } else {
    #pragma unroll
    for (int f = 0; f < H; ++f) p[f] = 0.f;
  }
  block_stats16(p, pmu, prs, wsum, wsq, G);
  float xn[H], z[H];
  #pragma unroll
  for (int f = 0; f < H; ++f) xn[f] = g1[f]*(p[f]-pmu[f])*prs[f] + be1[f];
  #pragma unroll
  for (int j = 0; j < H; ++j) z[j] = bl1[j];
  for (int k = 0; k < H; ++k){
    float xv = xn[k];
    #pragma unroll
    for (int j = 0; j < H; ++j) z[j] += xv * Wl1[k*H+j];
  }
  #pragma unroll
  for (int j = 0; j < H; ++j) z[j] = fmaxf(z[j], 0.f);
  block_stats16(z, smu, srs, wsum, wsq, G);
  float x2[2*H], z2[H];
  #pragma unroll
  for (int f = 0; f < H; ++f){
    x2[f]   = g2[f]  *(z[f]-smu[f])*srs[f] + be2[f];
    x2[H+f] = g2[H+f]*(p[f]-pmu[f])*prs[f] + be2[H+f];
  }
  #pragma unroll
  for (int j = 0; j < H; ++j) z2[j] = bl2[j];
  for (int k = 0; k < 2*H; ++k){
    float xv = x2[k];
    #pragma unroll
    for (int j = 0; j < H; ++j) z2[j] += xv * Wl2[k*H+j];
  }
  #pragma unroll
  for (int j = 0; j < H; ++j) z2[j] = fmaxf(z2[j], 0.f);
  block_stats16(z2, smu, srs, wsum, wsq, G);
  float x3[2*H], z3[H];
  #pragma unroll
  for (int f = 0; f < H; ++f){
    x3[f]   = g3[f]  *(z2[f]-smu[f])*srs[f] + be3[f];
    x3[H+f] = g3[H+f]*(p[f]-pmu[f])*prs[f] + be3[H+f];
  }
  #pragma unroll
  for (int j = 0; j < H; ++j) z3[j] = bl3[j];
  for (int k = 0; k < 2*H; ++k){
    float xv = x3[k];
    #pragma unroll
    for (int j = 0; j < H; ++j) z3[j] += xv * Wl3[k*H+j];
  }
  #pragma unroll
  for (int j = 0; j < H; ++j) z3[j] = fmaxf(z3[j], 0.f);
  if (g < G){
    float o = bo[0];
    #pragma unroll
    for (int j = 0; j < H; ++j) o += z3[j]*Wo[j];
    out[g] = o;
  }
}

extern "C" void kernel_launch(void* const* d_in, const int* in_sizes, int n_in,
                              void* d_out, int out_size, void* d_ws, size_t ws_size,
                              hipStream_t stream) {
  const float* x     = (const float*)d_in[0];
  const int*   ei    = (const int*)d_in[1];
  const float* attr  = (const float*)d_in[2];
  const int*   batch = (const int*)d_in[3];
  const float* W1  = (const float*)d_in[4];
  const float* We1 = (const float*)d_in[5];
  const float* as1 = (const float*)d_in[6];
  const float* ad1 = (const float*)d_in[7];
  const float* ae1 = (const float*)d_in[8];
  const float* b1  = (const float*)d_in[9];
  const float* bn1g = (const float*)d_in[10];
  const float* bn1b = (const float*)d_in[11];
  const float* W2  = (const float*)d_in[12];
  const float* We2 = (const float*)d_in[13];
  const float* as2 = (const float*)d_in[14];
  const float* ad2 = (const float*)d_in[15];
  const float* ae2 = (const float*)d_in[16];
  const float* b2  = (const float*)d_in[17];
  const float* bnl1g = (const float*)d_in[18];
  const float* bnl1b = (const float*)d_in[19];
  const float* Wl1 = (const float*)d_in[20];
  const float* bl1 = (const float*)d_in[21];
  const float* bnl2g = (const float*)d_in[22];
  const float* bnl2b = (const float*)d_in[23];
  const float* Wl2 = (const float*)d_in[24];
  const float* bl2 = (const float*)d_in[25];
  const float* bnl3g = (const float*)d_in[26];
  const float* bnl3b = (const float*)d_in[27];
  const float* Wl3 = (const float*)d_in[28];
  const float* bl3 = (const float*)d_in[29];
  const float* Wo  = (const float*)d_in[30];
  const float* bo  = (const float*)d_in[31];

  int N = in_sizes[0] / NF;
  int E = in_sizes[1] / 2;
  int G = out_size;
  const int* srcp = ei;
  const int* dstp = ei + E;

  int B     = (N + 63) >> 6;                         // 64-node buckets (2344)
  int M     = B * NB;                                // count-matrix size (600064)
  int chunk = (E + NB - 1) / NB;                     // edges per binning block (18750)
  int nbN   = (N + TPB - 1)/TPB;
  int nbS   = (M + SBLK*SITEMS - 1)/(SBLK*SITEMS);   // scan blocks (147 <= 256)

  // ---- workspace layout (rec persists through both GAT layers; no aliasing) ----
  char* wsb = (char*)d_ws;
  int2*  rec = (int2*)wsb;                           // 8B * E
  char* p = wsb + (size_t)8*E;
  __half* A = (__half*)p;     p += (size_t)2*H*N;    // h table (fp16, 4.8 MB)
  float* Bv  = (float*)p;     p += (size_t)16*N*4;   // layer output (fp32)
  float* asn = (float*)p;     p += (size_t)N*4;
  float* adn = (float*)p;     p += (size_t)N*4;
  int*   cnt     = (int*)p;   p += (size_t)4*M;      // per-(bucket,block) counts -> bases
  int*   cntT    = (int*)p;   p += (size_t)4*M;      // transposed bases [blk][b]
  int*   bbase   = (int*)p;   p += (size_t)4*(B+1);
  int*   part    = (int*)p;   p += (size_t)4*256;
  float* par     = (float*)p; p += 4*64;             // [0..3]=wp [4..19]=scale [20..35]=shift
  float* pooled  = (float*)p; p += (size_t)4*G*H;
  float* gcnt    = (float*)p; p += (size_t)4*G;
  float* partial = (float*)p; p += (size_t)4*nbN*32;

  float* bnscale = par + 4;
  float* bnshift = par + 20;

  // zero-init (ws is re-poisoned 0xAA before every launch)
  hipMemsetAsync(pooled, 0, (size_t)(G*H + G)*sizeof(float), stream);

  k_prep<<<1, 64, 0, stream>>>(We1, ae1, We2, ae2, par);

  // ---- binning: two-pass exclusive-range, 8B records, no global atomics ----
  k_bcount<<<NB, BTPB, 0, stream>>>(dstp, cnt, E, B, chunk);
  k_scan1<<<nbS, SBLK, 0, stream>>>(cnt, part, M);
  k_scan2<<<1, SBLK, 0, stream>>>(part, nbS, bbase, B, E);
  k_scan3<<<nbS, SBLK, 0, stream>>>(cnt, part, bbase, cntT, B, M);
  k_bwrite<<<NB, BTPB, 0, stream>>>(srcp, dstp, attr, par, cntT, rec, E, B, chunk);

  // ---- layer 1 ----
  k_node1<<<nbN, TPB, 0, stream>>>(x, W1, as1, ad1, A, asn, adn, N);
  k_gatf<0><<<B, GTPB, 0, stream>>>(rec, bbase, asn, adn, A, b1, Bv, N);
  k_stats<<<nbN, TPB, 0, stream>>>(Bv, partial, N);
  k_bnprep<<<1, 256, 0, stream>>>(partial, nbN, bn1g, bn1b, bnscale, bnshift, N);

  // ---- layer 2 ----
  k_node2<<<nbN, TPB, 0, stream>>>(Bv, bnscale, bnshift, W2, as2, ad2, A, asn, adn, N);
  k_gatf<1><<<B, GTPB, 0, stream>>>(rec, bbase, asn, adn, A, b2, Bv, N);

  // ---- pool + head ----
  k_pool<<<nbN, TPB, 0, stream>>>(Bv, batch, pooled, gcnt, N);
  k_head<<<1, 512, 0, stream>>>(pooled, gcnt, bnl1g, bnl1b, Wl1, bl1, bnl2g, bnl2b, Wl2, bl2,
                                bnl3g, bnl3b, Wl3, bl3, Wo, bo, (float*)d_out, G);
}

// Round 12
// 467.954 us; speedup vs baseline: 1.0757x; 1.0008x over previous
//
#include <hip/hip_runtime.h>
#include <hip/hip_fp16.h>
#include <math.h>

#define H 16
#define NF 64
#define TPB 256
#define NB 256        // binning blocks (1/CU)
#define NBSHIFT 8     // log2(NB)
#define BTPB 1024     // binning threads per block
#define GTPB 512      // gat threads per block (64 nodes x 8 lanes)
#define NSHIFT 6      // bucket = 64 consecutive dst nodes
#define MAXB 2560     // LDS counter capacity (B = ceil(150000/64) = 2344)
#define SBLK 256
#define SITEMS 16     // scan: 4096/block; M=2344*256=600064 -> 147 blocks <= 256
#define SRCMASK 0x3FFFF
#define CAP 2432      // bucket record capacity (mean 2048, sigma~45 -> +8.5σ);
                      // 2x int2[CAP] = 38KB LDS -> 4 blocks/CU = 32-wave cap
#define STAGE_CAP 18752  // >= chunk = ceil(E/NB) = 18750
#define PSPAN 96      // max graphs a 256-node block can span (typ. 2-3)

__device__ __forceinline__ float lrelu(float v){ return v > 0.f ? v : 0.2f*v; }

// ---- derived edge-attention weights: par[0..1] = We1@ae1, par[2..3] = We2@ae2 ----
__global__ void k_prep(const float* __restrict__ We1, const float* __restrict__ ae1,
                       const float* __restrict__ We2, const float* __restrict__ ae2,
                       float* __restrict__ params){
  int t = threadIdx.x;
  if (t < 4){
    const float* We = (t < 2) ? We1 : We2;
    const float* ae = (t < 2) ? ae1 : ae2;
    int r = t & 1;
    float s = 0.f;
    for (int c = 0; c < H; ++c) s += We[r*H + c] * ae[c];
    params[t] = s;
  }
}

// ---- pass 1: per-(bucket, block) histogram in LDS ----
__global__ __launch_bounds__(BTPB) void k_bcount(const int* __restrict__ dst,
    int* __restrict__ cnt, int E, int B, int chunk){
  __shared__ int lcnt[MAXB];
  int blk = blockIdx.x, t = threadIdx.x;
  for (int i = t; i < B; i += BTPB) lcnt[i] = 0;
  __syncthreads();
  int e0 = blk*chunk, e1 = min(E, e0 + chunk);
  for (int e = e0 + t; e < e1; e += BTPB){
    int d = __builtin_nontemporal_load(dst + e);   // NT: don't pollute L2
    atomicAdd(&lcnt[d >> NSHIFT], 1);
  }
  __syncthreads();
  for (int i = t; i < B; i += BTPB) cnt[(size_t)i*NB + blk] = lcnt[i];
}

// ---- scan of the count matrix (bucket-major) -> exclusive ranges ----
__global__ __launch_bounds__(SBLK) void k_scan1(const int* __restrict__ cnt,
    int* __restrict__ part, int M){
  __shared__ int red[SBLK];
  int base = blockIdx.x*SBLK*SITEMS;
  int t = threadIdx.x;
  int s = 0;
  for (int i = 0; i < SITEMS; ++i){
    int idx = base + t*SITEMS + i;
    s += (idx < M) ? cnt[idx] : 0;
  }
  red[t] = s; __syncthreads();
  for (int off = SBLK/2; off > 0; off >>= 1){
    if (t < off) red[t] += red[t+off];
    __syncthreads();
  }
  if (t == 0) part[blockIdx.x] = red[0];
}

__global__ __launch_bounds__(SBLK) void k_scan2(int* __restrict__ part, int nb,
    int* __restrict__ bbase, int B, int E){
  __shared__ int sh[SBLK];
  int t = threadIdx.x;
  int v = (t < nb) ? part[t] : 0;
  sh[t] = v; __syncthreads();
  for (int off = 1; off < SBLK; off <<= 1){
    int add = (t >= off) ? sh[t-off] : 0;
    __syncthreads();
    sh[t] += add;
    __syncthreads();
  }
  if (t < nb) part[t] = sh[t] - v;   // exclusive block offsets
  if (t == 0) bbase[B] = E;
}

// also emits the TRANSPOSED base matrix cntT[blk*B + b] so k_bwrite can read
// its column as two sequential rows (count = next base - base).
__global__ __launch_bounds__(SBLK) void k_scan3(int* __restrict__ cnt,
    const int* __restrict__ part, int* __restrict__ bbase,
    int* __restrict__ cntT, int B, int M){
  __shared__ int sh[SBLK];
  int base = blockIdx.x*SBLK*SITEMS;
  int t = threadIdx.x;
  int loc[SITEMS]; int s = 0;
  for (int i = 0; i < SITEMS; ++i){
    int idx = base + t*SITEMS + i;
    loc[i] = s;
    s += (idx < M) ? cnt[idx] : 0;
  }
  sh[t] = s; __syncthreads();
  for (int off = 1; off < SBLK; off <<= 1){
    int add = (t >= off) ? sh[t-off] : 0;
    __syncthreads();
    sh[t] += add;
    __syncthreads();
  }
  int toff = sh[t] - s + part[blockIdx.x];
  for (int i = 0; i < SITEMS; ++i){
    int idx = base + t*SITEMS + i;
    if (idx < M){
      int excl = toff + loc[i];
      cnt[idx] = excl;                               // in-place per-(bucket,block) base
      cntT[(size_t)(idx & (NB-1))*B + (idx >> NBSHIFT)] = excl;
      if ((idx & (NB-1)) == 0) bbase[idx / NB] = excl;
    }
  }
}

// ---- pass 2: LDS counting-sort of the block's chunk, then BURST write-out.
//      Each (bucket,block) segment of rec is written once, contiguously, by
//      consecutive lanes -> no partial-line thrash. Local per-bucket counts are
//      derived from consecutive exclusive bases in cntT (no histogram pass). ----
__global__ __launch_bounds__(BTPB) void k_bwrite(const int* __restrict__ src,
    const int* __restrict__ dst, const float* __restrict__ attr, const float* __restrict__ wp,
    const int* __restrict__ cntT, int2* __restrict__ rec, int E, int B, int chunk){
  __shared__ int2 stage[STAGE_CAP];
  __shared__ int ex[MAXB];
  __shared__ int wsum[16];
  int blk = blockIdx.x, t = threadIdx.x;
  const int* row0 = cntT + (size_t)blk*B;
  const int* row1 = cntT + (size_t)(blk+1)*B;
  // local exclusive scan of this block's per-bucket counts (ITEMS=3, 3072 >= B)
  {
    int v[3]; int s = 0;
    int base3 = t*3;
    #pragma unroll
    for (int i = 0; i < 3; ++i){
      int idx = base3 + i;
      int c = 0;
      if (idx < B){
        int g0 = row0[idx];
        int g1;
        if (blk < NB-1)      g1 = row1[idx];
        else if (idx < B-1)  g1 = cntT[idx+1];   // row 0 of next bucket
        else                 g1 = E;
        c = g1 - g0;
      }
      v[i] = c; s += c;
    }
    int lane = t & 63, wave = t >> 6;
    int x = s;
    for (int o = 1; o < 64; o <<= 1){
      int y = __shfl_up(x, o);
      if (lane >= o) x += y;
    }
    if (lane == 63) wsum[wave] = x;
    __syncthreads();
    if (t < 16){
      int w = wsum[t];
      int xx = w;
      for (int o = 1; o < 16; o <<= 1){
        int y = __shfl_up(xx, o);
        if (t >= o) xx += y;
      }
      wsum[t] = xx - w;   // exclusive wave base
    }
    __syncthreads();
    int run = wsum[wave] + (x - s);
    #pragma unroll
    for (int i = 0; i < 3; ++i){
      int idx = base3 + i;
      if (idx < B) ex[idx] = run;
      run += v[i];
    }
  }
  __syncthreads();
  // single edge pass: compute record, scatter into LDS at sorted position
  float w0 = wp[0], w1 = wp[1], w2 = wp[2], w3 = wp[3];
  int e0 = blk*chunk, e1 = min(E, e0 + chunk);
  for (int e = e0 + t; e < e1; e += BTPB){
    int d = __builtin_nontemporal_load(dst + e);
    int s = __builtin_nontemporal_load(src + e);
    union { double dd; float2 ff; } u;
    u.dd = __builtin_nontemporal_load((const double*)attr + e);
    float2 a = u.ff;
    int b = d >> NSHIFT;
    __half h1 = __float2half_rn(a.x*w0 + a.y*w1);
    __half h2 = __float2half_rn(a.x*w2 + a.y*w3);
    unsigned uu = (unsigned)__half_as_ushort(h1) | ((unsigned)__half_as_ushort(h2) << 16);
    int pos = atomicAdd(&ex[b], 1);
    stage[pos] = make_int2(s | ((d & 63) << 18), (int)uu);
  }
  __syncthreads();
  // burst write-out: 8 lanes per bucket; segments are contiguous in rec
  int grp = t >> 3, l8 = t & 7;
  for (int b = grp; b < B; b += (BTPB/8)){
    int start = (b == 0) ? 0 : ex[b-1];   // ex advanced by count during scatter
    int end = ex[b];
    if (start == end) continue;
    int gb = row0[b];
    for (int j = start + l8; j < end; j += 8)
      rec[(size_t)gb + (j - start)] = stage[j];
  }
}

// ---- fused GAT: per-bucket LDS RECORD-sort + softmax aggregate ----
// 512 threads = 64 nodes x 8 lanes (lane = feature PAIR, half2 loads).
// Phase A 2-way batched: both NT rec loads issue before either is consumed,
// overlapping the ~900-cycle HBM (L2-bypass) latency.
template<int SEL>
__global__ __launch_bounds__(GTPB) void k_gatf(const int2* __restrict__ rec,
    const int* __restrict__ bbase, const float* __restrict__ asn, const float* __restrict__ adn,
    const __half* __restrict__ h, const float* __restrict__ bias,
    float* __restrict__ out, int N){
  __shared__ int2 stage[CAP];    // raw: {src|ld<<18, w bits}
  __shared__ int2 sorted[CAP];   // sorted by ld
  __shared__ int lcnt[64], lcur[64], sr[2];
  __shared__ float sadn[64], sbias[H], sdacc[64];
  int b = blockIdx.x, t = threadIdx.x;
  int node0 = b << NSHIFT;
  if (t < 2) sr[t] = bbase[b + t];
  if (t < 64){
    lcnt[t] = 0;
    sdacc[t] = 0.f;
    int nn = node0 + t;
    sadn[t] = (nn < N) ? adn[nn] : 0.f;
  }
  if (t >= 64 && t < 64 + H) sbias[t - 64] = bias[t - 64];
  __syncthreads();
  int r0 = sr[0], cnt = sr[1] - r0;
  // phase A: 2-way batched NT loads, decode, asn gather, exp, histogram + sd
  for (int i = t; i < cnt; i += 2*GTPB){
    int i2 = i + GTPB;
    long long raw0 = __builtin_nontemporal_load((const long long*)(rec + r0 + i));
    long long raw1 = 0;
    bool has2 = (i2 < cnt);
    if (has2) raw1 = __builtin_nontemporal_load((const long long*)(rec + r0 + i2));
    {
      int rx = (int)(unsigned)(raw0 & 0xFFFFFFFFll);
      unsigned u = (unsigned)((unsigned long long)raw0 >> 32);
      int ld = ((unsigned)rx) >> 18;
      float d = __half2float(__ushort_as_half((unsigned short)(SEL ? (u >> 16) : (u & 0xFFFFu))));
      float w = __expf(lrelu(asn[rx & SRCMASK] + sadn[ld] + d));
      stage[i] = make_int2(rx, __float_as_int(w));
      atomicAdd(&lcnt[ld], 1);
      atomicAdd(&sdacc[ld], d);
    }
    if (has2){
      int rx = (int)(unsigned)(raw1 & 0xFFFFFFFFll);
      unsigned u = (unsigned)((unsigned long long)raw1 >> 32);
      int ld = ((unsigned)rx) >> 18;
      float d = __half2float(__ushort_as_half((unsigned short)(SEL ? (u >> 16) : (u & 0xFFFFu))));
      float w = __expf(lrelu(asn[rx & SRCMASK] + sadn[ld] + d));
      stage[i2] = make_int2(rx, __float_as_int(w));
      atomicAdd(&lcnt[ld], 1);
      atomicAdd(&sdacc[ld], d);
    }
  }
  __syncthreads();
  // exclusive scan over 64 node counters (wave 0)
  if (t < 64){
    int v = lcnt[t];
    int x = v;
    for (int o = 1; o < 64; o <<= 1){
      int y = __shfl_up(x, o);
      if (t >= o) x += y;
    }
    lcur[t] = x - v;
  }
  __syncthreads();
  // phase C: pure LDS scatter of full records to sorted positions
  for (int i = t; i < cnt; i += GTPB){
    int2 r = stage[i];
    sorted[atomicAdd(&lcur[((unsigned)r.x) >> 18], 1)] = r;
  }
  __syncthreads();
  int nl = t >> 3, l2 = t & 7;     // node, feature-pair lane
  int n = node0 + nl;
  if (n >= N) return;
  const __half2* h2 = (const __half2*)h;
  float b0 = sbias[2*l2], b1 = sbias[2*l2 + 1];
  int deg = lcnt[nl];
  int s0 = lcur[nl] - deg;          // lcur advanced by deg during scatter
  float den = 0.f, acc0 = 0.f, acc1 = 0.f;
  for (int j = 0; j < deg; ++j){
    int2 r = sorted[s0 + j];
    float w = __int_as_float(r.y);
    float2 f = __half22float2(h2[(size_t)(r.x & SRCMASK)*8 + l2]);
    den += w;
    acc0 += w * f.x;
    acc1 += w * f.y;
  }
  // self-loop: edge_attr = mean of incoming attr -> dot = mean of incoming dots
  float lael = sdacc[nl] / fmaxf((float)deg, 1.f);
  float wl = __expf(lrelu(asn[n] + sadn[nl] + lael));
  float2 fs = __half22float2(h2[(size_t)n*8 + l2]);
  den += wl;
  acc0 += wl * fs.x;
  acc1 += wl * fs.y;
  float inv = 1.f / (den + 1e-16f);
  ((float2*)out)[(size_t)n*8 + l2] =
      make_float2(fmaxf(acc0*inv + b0, 0.f), fmaxf(acc1*inv + b1, 0.f));
}

// ---- layer-1 node transform: h = x @ W1 (stored fp16), alpha_src/dst (fp32) ----
__global__ __launch_bounds__(TPB) void k_node1(const float* __restrict__ x, const float* __restrict__ W,
    const float* __restrict__ av_s, const float* __restrict__ av_d,
    __half* __restrict__ hout, float* __restrict__ asn, float* __restrict__ adn, int N){
  __shared__ float sW[NF*H];
  __shared__ float sas[H], sad[H];
  int t = threadIdx.x;
  for (int i = t; i < NF*H; i += TPB) sW[i] = W[i];
  if (t < H){ sas[t] = av_s[t]; sad[t] = av_d[t]; }
  __syncthreads();
  int n = blockIdx.x*TPB + t;
  if (n >= N) return;
  float h[H];
  #pragma unroll
  for (int j = 0; j < H; ++j) h[j] = 0.f;
  const float4* xr = (const float4*)(x + (size_t)n*NF);
  #pragma unroll
  for (int k4 = 0; k4 < NF/4; ++k4){
    float4 xv = xr[k4];
    #pragma unroll
    for (int j = 0; j < H; ++j){
      h[j] += xv.x*sW[(4*k4+0)*H+j] + xv.y*sW[(4*k4+1)*H+j]
            + xv.z*sW[(4*k4+2)*H+j] + xv.w*sW[(4*k4+3)*H+j];
    }
  }
  union { int4 i4[2]; __half hh[H]; } pk;
  #pragma unroll
  for (int j = 0; j < H; ++j) pk.hh[j] = __float2half_rn(h[j]);
  int4* ho = (int4*)(hout + (size_t)n*H);
  ho[0] = pk.i4[0]; ho[1] = pk.i4[1];
  float ss = 0.f, sd = 0.f;
  #pragma unroll
  for (int j = 0; j < H; ++j){ ss += h[j]*sas[j]; sd += h[j]*sad[j]; }
  asn[n] = ss; adn[n] = sd;
}

// ---- BN sum/sumsq: per-block partials, zero global atomics ----
__global__ __launch_bounds__(TPB) void k_stats(const float* __restrict__ B,
    float* __restrict__ partial, int N){
  __shared__ float lds[4][32];
  int t = threadIdx.x;
  int n = blockIdx.x*TPB + t;
  float v[H];
  if (n < N){
    const float4* br = (const float4*)(B + (size_t)n*H);
    float4 a0 = br[0], a1 = br[1], a2 = br[2], a3 = br[3];
    v[0]=a0.x; v[1]=a0.y; v[2]=a0.z; v[3]=a0.w;
    v[4]=a1.x; v[5]=a1.y; v[6]=a1.z; v[7]=a1.w;
    v[8]=a2.x; v[9]=a2.y; v[10]=a2.z; v[11]=a2.w;
    v[12]=a3.x; v[13]=a3.y; v[14]=a3.z; v[15]=a3.w;
  } else {
    #pragma unroll
    for (int f = 0; f < H; ++f) v[f] = 0.f;
  }
  float s[H], q[H];
  #pragma unroll
  for (int f = 0; f < H; ++f){ s[f] = v[f]; q[f] = v[f]*v[f]; }
  for (int m = 1; m < 64; m <<= 1){
    #pragma unroll
    for (int f = 0; f < H; ++f){
      s[f] += __shfl_xor(s[f], m);
      q[f] += __shfl_xor(q[f], m);
    }
  }
  int wave = t >> 6, lane = t & 63;
  if (lane == 0){
    #pragma unroll
    for (int f = 0; f < H; ++f){ lds[wave][f] = s[f]; lds[wave][H+f] = q[f]; }
  }
  __syncthreads();
  if (t < 32)
    partial[(size_t)blockIdx.x*32 + t] = lds[0][t] + lds[1][t] + lds[2][t] + lds[3][t];
}

// ---- final BN reduction over block partials + scale/shift ----
__global__ __launch_bounds__(256) void k_bnprep(const float* __restrict__ partial, int nb,
    const float* __restrict__ gamma, const float* __restrict__ beta,
    float* __restrict__ scale, float* __restrict__ shift, int N){
  __shared__ float red[256];
  __shared__ float tot[32];
  int t = threadIdx.x;
  int f = t & 31, c = t >> 5;        // 8 chunks x 32 features
  float s = 0.f;
  for (int b = c; b < nb; b += 8) s += partial[(size_t)b*32 + f];
  red[c*32 + f] = s;
  __syncthreads();
  if (t < 32){
    float S = 0.f;
    #pragma unroll
    for (int cc = 0; cc < 8; ++cc) S += red[cc*32 + t];
    tot[t] = S;
  }
  __syncthreads();
  if (t < H){
    float inv = 1.f / (float)N;
    float mu  = tot[t] * inv;
    float var = tot[H+t] * inv - mu*mu;
    float sc  = gamma[t] * rsqrtf(var + 1e-5f);
    scale[t] = sc;
    shift[t] = beta[t] - mu*sc;
  }
}

// ---- layer-2 node transform: BN + h = xn @ W2 (stored fp16) + alphas ----
__global__ __launch_bounds__(TPB) void k_node2(const float* __restrict__ Bin, const float* __restrict__ scale,
    const float* __restrict__ shift, const float* __restrict__ W,
    const float* __restrict__ av_s, const float* __restrict__ av_d,
    __half* __restrict__ hout, float* __restrict__ asn, float* __restrict__ adn, int N){
  __shared__ float sW[H*H];
  __shared__ float ssc[H], ssh[H], sas[H], sad[H];
  int t = threadIdx.x;
  if (t < H*H) sW[t] = W[t];
  if (t < H){ ssc[t] = scale[t]; ssh[t] = shift[t]; sas[t] = av_s[t]; sad[t] = av_d[t]; }
  __syncthreads();
  int n = blockIdx.x*TPB + t;
  if (n >= N) return;
  const float4* br = (const float4*)(Bin + (size_t)n*H);
  float4 a0 = br[0], a1 = br[1], a2 = br[2], a3 = br[3];
  float xn[H] = {a0.x,a0.y,a0.z,a0.w, a1.x,a1.y,a1.z,a1.w,
                 a2.x,a2.y,a2.z,a2.w, a3.x,a3.y,a3.z,a3.w};
  #pragma unroll
  for (int f = 0; f < H; ++f) xn[f] = xn[f]*ssc[f] + ssh[f];
  float h[H];
  #pragma unroll
  for (int j = 0; j < H; ++j) h[j] = 0.f;
  #pragma unroll
  for (int k = 0; k < H; ++k){
    float xv = xn[k];
    #pragma unroll
    for (int j = 0; j < H; ++j) h[j] += xv * sW[k*H+j];
  }
  union { int4 i4[2]; __half hh[H]; } pk;
  #pragma unroll
  for (int j = 0; j < H; ++j) pk.hh[j] = __float2half_rn(h[j]);
  int4* ho = (int4*)(hout + (size_t)n*H);
  ho[0] = pk.i4[0]; ho[1] = pk.i4[1];
  float ss = 0.f, sd = 0.f;
  #pragma unroll
  for (int j = 0; j < H; ++j){ ss += h[j]*sas[j]; sd += h[j]*sad[j]; }
  asn[n] = ss; adn[n] = sd;
}

// ---- mean-pool: LDS per-block segmented partials (batch sorted -> block spans
//      a contiguous graph range, typ. 2-3). One global atomicAdd per
//      (touched graph, feature) per block instead of per-lane atomics. ----
__global__ __launch_bounds__(TPB) void k_pool(const float* __restrict__ B,
    const int* __restrict__ batch, float* __restrict__ pooled, float* __restrict__ gcnt, int N){
  __shared__ float acc[PSPAN*H];
  __shared__ float cacc[PSPAN];
  __shared__ int sg[2];
  int t = threadIdx.x;
  int n0 = blockIdx.x*TPB;
  int n = n0 + t;
  if (t == 0){
    sg[0] = batch[n0];
    int n1 = min(n0 + TPB - 1, N - 1);
    sg[1] = batch[n1];
  }
  __syncthreads();
  int gmin = sg[0];
  int span = sg[1] - gmin + 1;
  bool fits = (span <= PSPAN);        // block-uniform
  if (fits){
    for (int i = t; i < span*H; i += TPB) acc[i] = 0.f;
    for (int i = t; i < span; i += TPB) cacc[i] = 0.f;
    __syncthreads();
  }
  int lane = t & 63;
  bool valid = n < N;
  int g = valid ? batch[n] : -1;
  float v[H];
  if (valid){
    const float4* br = (const float4*)(B + (size_t)n*H);
    float4 a0 = br[0], a1 = br[1], a2 = br[2], a3 = br[3];
    v[0]=a0.x; v[1]=a0.y; v[2]=a0.z; v[3]=a0.w;
    v[4]=a1.x; v[5]=a1.y; v[6]=a1.z; v[7]=a1.w;
    v[8]=a2.x; v[9]=a2.y; v[10]=a2.z; v[11]=a2.w;
    v[12]=a3.x; v[13]=a3.y; v[14]=a3.z; v[15]=a3.w;
  } else {
    #pragma unroll
    for (int f = 0; f < H; ++f) v[f] = 0.f;
  }
  int g0 = __shfl(g, 0);
  bool allsame = __all(valid && g == g0);
  if (fits){
    if (allsame){
      float s[H];
      #pragma unroll
      for (int f = 0; f < H; ++f) s[f] = v[f];
      for (int m = 1; m < 64; m <<= 1){
        #pragma unroll
        for (int f = 0; f < H; ++f) s[f] += __shfl_xor(s[f], m);
      }
      if (lane == 0){
        float* p = acc + (g0 - gmin)*H;
        #pragma unroll
        for (int f = 0; f < H; ++f) atomicAdd(&p[f], s[f]);
        atomicAdd(&cacc[g0 - gmin], 64.f);
      }
    } else if (valid){
      float* p = acc + (g - gmin)*H;
      #pragma unroll
      for (int f = 0; f < H; ++f) atomicAdd(&p[f], v[f]);
      atomicAdd(&cacc[g - gmin], 1.f);
    }
    __syncthreads();
    // flush block partials: ~span*17 global atomics, low per-address multiplicity
    for (int i = t; i < span*H; i += TPB){
      float a = acc[i];
      if (a != 0.f) atomicAdd(&pooled[(size_t)gmin*H + i], a);
    }
    for (int i = t; i < span; i += TPB){
      float c = cacc[i];
      if (c != 0.f) atomicAdd(&gcnt[gmin + i], c);
    }
  } else {
    // safety fallback (never expected): direct global atomics
    if (allsame){
      float s[H];
      #pragma unroll
      for (int f = 0; f < H; ++f) s[f] = v[f];
      for (int m = 1; m < 64; m <<= 1){
        #pragma unroll
        for (int f = 0; f < H; ++f) s[f] += __shfl_xor(s[f], m);
      }
      if (lane == 0){
        float* p = pooled + (size_t)g0*H;
        #pragma unroll
        for (int f = 0; f < H; ++f) atomicAdd(&p[f], s[f]);
        atomicAdd(&gcnt[g0], 64.f);
      }
    } else if (valid){
      float* p = pooled + (size_t)g*H;
      #pragma unroll
      for (int f = 0; f < H; ++f) atomicAdd(&p[f], v[f]);
      atomicAdd(&gcnt[g], 1.f);
    }
  }
}

// ---- D2RL head: one block of 512 threads (one per graph) ----
__device__ void block_stats16(const float* v, float* mu, float* rs,
                              float* wsum, float* wsq, int G){
  float s[H], q[H];
  #pragma unroll
  for (int f = 0; f < H; ++f){ s[f] = v[f]; q[f] = v[f]*v[f]; }
  for (int m = 1; m < 64; m <<= 1){
    #pragma unroll
    for (int f = 0; f < H; ++f){
      s[f] += __shfl_xor(s[f], m);
      q[f] += __shfl_xor(q[f], m);
    }
  }
  int wave = threadIdx.x >> 6, lane = threadIdx.x & 63;
  if (lane == 0){
    #pragma unroll
    for (int f = 0; f < H; ++f){ wsum[wave*H+f] = s[f]; wsq[wave*H+f] = q[f]; }
  }
  __syncthreads();
  int t = threadIdx.x;
  if (t < H){
    float S = 0.f, Q = 0.f;
    for (int w = 0; w < 8; ++w){ S += wsum[w*H+t]; Q += wsq[w*H+t]; }
    float m_ = S / (float)G;
    float var = Q / (float)G - m_*m_;
    mu[t] = m_;
    rs[t] = rsqrtf(var + 1e-5f);
  }
  __syncthreads();
}

__global__ __launch_bounds__(512) void k_head(const float* __restrict__ pooled, const float* __restrict__ gcnt,
    const float* __restrict__ g1, const float* __restrict__ be1,
    const float* __restrict__ Wl1, const float* __restrict__ bl1,
    const float* __restrict__ g2, const float* __restrict__ be2,
    const float* __restrict__ Wl2, const float* __restrict__ bl2,
    const float* __restrict__ g3, const float* __restrict__ be3,
    const float* __restrict__ Wl3, const float* __restrict__ bl3,
    const float* __restrict__ Wo, const float* __restrict__ bo,
    float* __restrict__ out, int G){
  __shared__ float wsum[8*H], wsq[8*H];
  __shared__ float pmu[H], prs[H], smu[H], srs[H];
  int g = threadIdx.x;
  float p[H];
  if (g < G){
    float c = fmaxf(gcnt[g], 1.f);
    #pragma unroll
    for (int f = 0; f < H; ++f) p[f] = pooled[(size_t)g*H+f] / c;
  } else {
    #pragma unroll
    for (int f = 0; f < H; ++f) p[f] = 0.f;
  }
  block_stats16(p, pmu, prs, wsum, wsq, G);
  float xn[H], z[H];
  #pragma unroll
  for (int f = 0; f < H; ++f) xn[f] = g1[f]*(p[f]-pmu[f])*prs[f] + be1[f];
  #pragma unroll
  for (int j = 0; j < H; ++j) z[j] = bl1[j];
  for (int k = 0; k < H; ++k){
    float xv = xn[k];
    #pragma unroll
    for (int j = 0; j < H; ++j) z[j] += xv * Wl1[k*H+j];
  }
  #pragma unroll
  for (int j = 0; j < H; ++j) z[j] = fmaxf(z[j], 0.f);
  block_stats16(z, smu, srs, wsum, wsq, G);
  float x2[2*H], z2[H];
  #pragma unroll
  for (int f = 0; f < H; ++f){
    x2[f]   = g2[f]  *(z[f]-smu[f])*srs[f] + be2[f];
    x2[H+f] = g2[H+f]*(p[f]-pmu[f])*prs[f] + be2[H+f];
  }
  #pragma unroll
  for (int j = 0; j < H; ++j) z2[j] = bl2[j];
  for (int k = 0; k < 2*H; ++k){
    float xv = x2[k];
    #pragma unroll
    for (int j = 0; j < H; ++j) z2[j] += xv * Wl2[k*H+j];
  }
  #pragma unroll
  for (int j = 0; j < H; ++j) z2[j] = fmaxf(z2[j], 0.f);
  block_stats16(z2, smu, srs, wsum, wsq, G);
  float x3[2*H], z3[H];
  #pragma unroll
  for (int f = 0; f < H; ++f){
    x3[f]   = g3[f]  *(z2[f]-smu[f])*srs[f] + be3[f];
    x3[H+f] = g3[H+f]*(p[f]-pmu[f])*prs[f] + be3[H+f];
  }
  #pragma unroll
  for (int j = 0; j < H; ++j) z3[j] = bl3[j];
  for (int k = 0; k < 2*H; ++k){
    float xv = x3[k];
    #pragma unroll
    for (int j = 0; j < H; ++j) z3[j] += xv * Wl3[k*H+j];
  }
  #pragma unroll
  for (int j = 0; j < H; ++j) z3[j] = fmaxf(z3[j], 0.f);
  if (g < G){
    float o = bo[0];
    #pragma unroll
    for (int j = 0; j < H; ++j) o += z3[j]*Wo[j];
    out[g] = o;
  }
}

extern "C" void kernel_launch(void* const* d_in, const int* in_sizes, int n_in,
                              void* d_out, int out_size, void* d_ws, size_t ws_size,
                              hipStream_t stream) {
  const float* x     = (const float*)d_in[0];
  const int*   ei    = (const int*)d_in[1];
  const float* attr  = (const float*)d_in[2];
  const int*   batch = (const int*)d_in[3];
  const float* W1  = (const float*)d_in[4];
  const float* We1 = (const float*)d_in[5];
  const float* as1 = (const float*)d_in[6];
  const float* ad1 = (const float*)d_in[7];
  const float* ae1 = (const float*)d_in[8];
  const float* b1  = (const float*)d_in[9];
  const float* bn1g = (const float*)d_in[10];
  const float* bn1b = (const float*)d_in[11];
  const float* W2  = (const float*)d_in[12];
  const float* We2 = (const float*)d_in[13];
  const float* as2 = (const float*)d_in[14];
  const float* ad2 = (const float*)d_in[15];
  const float* ae2 = (const float*)d_in[16];
  const float* b2  = (const float*)d_in[17];
  const float* bnl1g = (const float*)d_in[18];
  const float* bnl1b = (const float*)d_in[19];
  const float* Wl1 = (const float*)d_in[20];
  const float* bl1 = (const float*)d_in[21];
  const float* bnl2g = (const float*)d_in[22];
  const float* bnl2b = (const float*)d_in[23];
  const float* Wl2 = (const float*)d_in[24];
  const float* bl2 = (const float*)d_in[25];
  const float* bnl3g = (const float*)d_in[26];
  const float* bnl3b = (const float*)d_in[27];
  const float* Wl3 = (const float*)d_in[28];
  const float* bl3 = (const float*)d_in[29];
  const float* Wo  = (const float*)d_in[30];
  const float* bo  = (const float*)d_in[31];

  int N = in_sizes[0] / NF;
  int E = in_sizes[1] / 2;
  int G = out_size;
  const int* srcp = ei;
  const int* dstp = ei + E;

  int B     = (N + 63) >> 6;                         // 64-node buckets (2344)
  int M     = B * NB;                                // count-matrix size (600064)
  int chunk = (E + NB - 1) / NB;                     // edges per binning block (18750)
  int nbN   = (N + TPB - 1)/TPB;
  int nbS   = (M + SBLK*SITEMS - 1)/(SBLK*SITEMS);   // scan blocks (147 <= 256)

  // ---- workspace layout (rec persists through both GAT layers; no aliasing) ----
  char* wsb = (char*)d_ws;
  int2*  rec = (int2*)wsb;                           // 8B * E
  char* p = wsb + (size_t)8*E;
  __half* A = (__half*)p;     p += (size_t)2*H*N;    // h table (fp16, 4.8 MB)
  float* Bv  = (float*)p;     p += (size_t)16*N*4;   // layer output (fp32)
  float* asn = (float*)p;     p += (size_t)N*4;
  float* adn = (float*)p;     p += (size_t)N*4;
  int*   cnt     = (int*)p;   p += (size_t)4*M;      // per-(bucket,block) counts -> bases
  int*   cntT    = (int*)p;   p += (size_t)4*M;      // transposed bases [blk][b]
  int*   bbase   = (int*)p;   p += (size_t)4*(B+1);
  int*   part    = (int*)p;   p += (size_t)4*256;
  float* par     = (float*)p; p += 4*64;             // [0..3]=wp [4..19]=scale [20..35]=shift
  float* pooled  = (float*)p; p += (size_t)4*G*H;
  float* gcnt    = (float*)p; p += (size_t)4*G;
  float* partial = (float*)p; p += (size_t)4*nbN*32;

  float* bnscale = par + 4;
  float* bnshift = par + 20;

  // zero-init (ws is re-poisoned 0xAA before every launch)
  hipMemsetAsync(pooled, 0, (size_t)(G*H + G)*sizeof(float), stream);

  k_prep<<<1, 64, 0, stream>>>(We1, ae1, We2, ae2, par);

  // ---- binning: two-pass exclusive-range, 8B records, no global atomics ----
  k_bcount<<<NB, BTPB, 0, stream>>>(dstp, cnt, E, B, chunk);
  k_scan1<<<nbS, SBLK, 0, stream>>>(cnt, part, M);
  k_scan2<<<1, SBLK, 0, stream>>>(part, nbS, bbase, B, E);
  k_scan3<<<nbS, SBLK, 0, stream>>>(cnt, part, bbase, cntT, B, M);
  k_bwrite<<<NB, BTPB, 0, stream>>>(srcp, dstp, attr, par, cntT, rec, E, B, chunk);

  // ---- layer 1 ----
  k_node1<<<nbN, TPB, 0, stream>>>(x, W1, as1, ad1, A, asn, adn, N);
  k_gatf<0><<<B, GTPB, 0, stream>>>(rec, bbase, asn, adn, A, b1, Bv, N);
  k_stats<<<nbN, TPB, 0, stream>>>(Bv, partial, N);
  k_bnprep<<<1, 256, 0, stream>>>(partial, nbN, bn1g, bn1b, bnscale, bnshift, N);

  // ---- layer 2 ----
  k_node2<<<nbN, TPB, 0, stream>>>(Bv, bnscale, bnshift, W2, as2, ad2, A, asn, adn, N);
  k_gatf<1><<<B, GTPB, 0, stream>>>(rec, bbase, asn, adn, A, b2, Bv, N);

  // ---- pool + head ----
  k_pool<<<nbN, TPB, 0, stream>>>(Bv, batch, pooled, gcnt, N);
  k_head<<<1, 512, 0, stream>>>(pooled, gcnt, bnl1g, bnl1b, Wl1, bl1, bnl2g, bnl2b, Wl2, bl2,
                                bnl3g, bnl3b, Wl3, bl3, Wo, bo, (float*)d_out, G);
}